// Round 1
// baseline (1876.771 us; speedup 1.0000x reference)
//
#include <hip/hip_runtime.h>
#include <hip/hip_bf16.h>
#include <stdint.h>

#define NB 16
#define NN 2048
#define NC 64
#define NH 128
#define NK 16
#define NS (NB*NN)
#define NSK (NS*NK)
#define EPSV 1e-5f

typedef __attribute__((ext_vector_type(8))) short short8;
typedef __attribute__((ext_vector_type(4))) float f32x4;

__device__ __forceinline__ unsigned short f2bf(float x) {
  union { float f; unsigned u; } v; v.f = x;
  unsigned r = v.u + 0x7fffu + ((v.u >> 16) & 1u);
  return (unsigned short)(r >> 16);
}

__device__ __forceinline__ unsigned orderf(float f) {
  unsigned u = __float_as_uint(f);
  return (u & 0x80000000u) ? ~u : (u | 0x80000000u);
}

__device__ __forceinline__ unsigned long long shfl_xor_u64(unsigned long long v, int m) {
  unsigned lo = (unsigned)(v & 0xffffffffull);
  unsigned hi = (unsigned)(v >> 32);
  lo = __shfl_xor(lo, m, 64);
  hi = __shfl_xor(hi, m, 64);
  return (((unsigned long long)hi) << 32) | lo;
}

// ---------------- squared norms ----------------
__global__ void sq_kernel(const float* __restrict__ x, float* __restrict__ sq) {
  int i = blockIdx.x * blockDim.x + threadIdx.x;
  if (i >= NS) return;
  const float4* x4 = (const float4*)(x + (size_t)i * NC);
  float s = 0.f;
#pragma unroll
  for (int k = 0; k < NC/4; k++) {
    float4 v = x4[k];
    s += v.x*v.x + v.y*v.y + v.z*v.z + v.w*v.w;
  }
  sq[i] = s;
}

// ---------------- kNN: fp32 distances, exact ref formula, top-16 ----------------
// grid: NB * (NN/4) blocks of 256 (4 waves, 1 row per wave)
__global__ __launch_bounds__(256) void knn_kernel(const float* __restrict__ x,
                                                  const float* __restrict__ sq,
                                                  int* __restrict__ nbr) {
  __shared__ float colbuf[128 * 68];  // 128 cols x 64 ch, stride 68 (16B aligned, spread banks)
  __shared__ float sqcol[128];
  int b = blockIdx.x >> 9;            // / (NN/4=512)
  int rbase = (blockIdx.x & 511) << 2;
  int wave = threadIdx.x >> 6;
  int lane = threadIdx.x & 63;
  int row = rbase + wave;
  int grow = b * NN + row;

  float xr[64];
  const float4* xrp = (const float4*)(x + (size_t)grow * NC);
#pragma unroll
  for (int k = 0; k < 16; k++) {
    float4 v = xrp[k];
    xr[k*4+0]=v.x; xr[k*4+1]=v.y; xr[k*4+2]=v.z; xr[k*4+3]=v.w;
  }
  float sqr = sq[grow];

  unsigned long long keys[16];
#pragma unroll
  for (int i = 0; i < 16; i++) keys[i] = ~0ull;
  unsigned long long wkey = ~0ull;
  int wslot = 0;

  for (int ch = 0; ch < NN/128; ch++) {
    int cbase = ch * 128;
    __syncthreads();
    {
      int col = threadIdx.x >> 1, half = threadIdx.x & 1;
      const float4* cp = (const float4*)(x + (size_t)(b*NN + cbase + col) * NC) + half*8;
      float4* dst = (float4*)&colbuf[col*68 + half*32];
#pragma unroll
      for (int k = 0; k < 8; k++) dst[k] = cp[k];
      if (threadIdx.x < 128) sqcol[threadIdx.x] = sq[b*NN + cbase + threadIdx.x];
    }
    __syncthreads();
#pragma unroll
    for (int cc = 0; cc < 2; cc++) {
      int c = cc*64 + lane;
      const float* bp = &colbuf[c*68];
      float a0=0.f,a1=0.f,a2=0.f,a3=0.f;
#pragma unroll
      for (int k = 0; k < 16; k++) {
        float4 bv = *(const float4*)(bp + k*4);
        a0 = fmaf(xr[k*4+0], bv.x, a0);
        a1 = fmaf(xr[k*4+1], bv.y, a1);
        a2 = fmaf(xr[k*4+2], bv.z, a2);
        a3 = fmaf(xr[k*4+3], bv.w, a3);
      }
      float dot = (a0+a1)+(a2+a3);
      float d2 = sqr + sqcol[c] - 2.f*dot;
      unsigned long long key = ((unsigned long long)orderf(d2) << 32) |
                               (unsigned)(b*NN + cbase + c);
      if (key < wkey) {
        keys[wslot] = key;
        wkey = keys[0]; wslot = 0;
#pragma unroll
        for (int i = 1; i < 16; i++) if (keys[i] > wkey) { wkey = keys[i]; wslot = i; }
      }
    }
  }
  // merge top-16 across 64 lanes (registers + shuffles only)
  for (int j = 0; j < NK; j++) {
    unsigned long long m = keys[0];
#pragma unroll
    for (int i = 1; i < 16; i++) m = (keys[i] < m) ? keys[i] : m;
#pragma unroll
    for (int off = 1; off < 64; off <<= 1) {
      unsigned long long o = shfl_xor_u64(m, off);
      m = (o < m) ? o : m;
    }
#pragma unroll
    for (int i = 0; i < 16; i++) if (keys[i] == m) keys[i] = ~0ull;
    if (lane == 0) nbr[(size_t)grow * NK + j] = (int)(m & 0xffffffffu);
  }
}

// ---------------- weight prep: transpose + bf16 ----------------
__global__ void prep_weights(const float* __restrict__ sW1, const float* __restrict__ sW2,
                             const float* __restrict__ tW1, const float* __restrict__ tW2,
                             const float* __restrict__ fW,
                             unsigned short* __restrict__ sW1t, unsigned short* __restrict__ sW2t,
                             unsigned short* __restrict__ tW1t, unsigned short* __restrict__ tW2t,
                             unsigned short* __restrict__ fWt) {
  int i = blockIdx.x * blockDim.x + threadIdx.x;
  if (i < 4*16384) {
    int mi = i >> 14, e = i & 16383;
    int h = e >> 7, k = e & 127;
    const float* src = (mi==0) ? sW1 : (mi==1) ? sW2 : (mi==2) ? tW1 : tW2;
    unsigned short* dst = (mi==0) ? sW1t : (mi==1) ? sW2t : (mi==2) ? tW1t : tW2t;
    dst[h*128 + k] = f2bf(src[k*128 + h]);
  } else {
    int e = i - 4*16384;
    if (e < 128*256) {
      int h = e >> 8, k = e & 255;
      fWt[h*256 + k] = f2bf(fW[k*128 + h]);
    }
  }
}

// ---------------- fused EdgeConv MLP pass ----------------
// MODE 0: GEMM1 -> stats(h1)
// MODE 1: GEMM1 -> bn1+relu -> GEMM2 -> stats(h2)
// MODE 2: GEMM1 -> bn1+relu -> GEMM2 -> bn2+relu -> max over K -> xout
// grid 1024 x 128 threads (2 waves), each wg loops 8 tiles of 64 rows.
template<int MODE>
__global__ __launch_bounds__(128) void mlp_pass(
    const float* __restrict__ x,
    const int* __restrict__ nbr,
    const unsigned short* __restrict__ W1t,
    const unsigned short* __restrict__ W2t,
    const float* __restrict__ aff1,
    const float* __restrict__ aff2,
    float* __restrict__ stats,
    float* __restrict__ xout) {
  __shared__ unsigned short tile[64 * 128];  // e-tile, reused as a-tile
  int wave = threadIdx.x >> 6;
  int lane = threadIdx.x & 63;
  int n16 = lane & 15;
  int q = lane >> 4;
  int cb = wave * 64;

  float sc1[4], sh1[4], sc2[4], sh2[4];
  if (MODE >= 1) {
#pragma unroll
    for (int ci = 0; ci < 4; ci++) {
      int col = cb + ci*16 + n16;
      sc1[ci] = aff1[col]; sh1[ci] = aff1[128 + col];
    }
  }
  if (MODE == 2) {
#pragma unroll
    for (int ci = 0; ci < 4; ci++) {
      int col = cb + ci*16 + n16;
      sc2[ci] = aff2[col]; sh2[ci] = aff2[128 + col];
    }
  }
  float ps[4] = {0.f,0.f,0.f,0.f}, ps2[4] = {0.f,0.f,0.f,0.f};

  for (int it = 0; it < 8; it++) {
    int tileIdx = blockIdx.x * 8 + it;
    int s0 = tileIdx * 64;
    __syncthreads();
    // stage e-tile: rows s0..s0+63, k<64: bf16(xi); k>=64: bf16(xj-xi). XOR-swizzled 16B blocks.
    {
      int r = threadIdx.x >> 1, half = threadIdx.x & 1;
      int s = s0 + r;
      int node = s >> 4;
      if (half == 0) {
        const float4* xp = (const float4*)(x + (size_t)node * NC);
#pragma unroll
        for (int kk = 0; kk < 16; kk++) {
          float4 v = xp[kk];
          int kc8 = kk >> 1;
          int pos = ((kc8 ^ (r & 7)) << 3) + ((kk & 1) << 2);
          unsigned short* d = &tile[r*128 + pos];
          d[0]=f2bf(v.x); d[1]=f2bf(v.y); d[2]=f2bf(v.z); d[3]=f2bf(v.w);
        }
      } else {
        int ng = nbr[s];
        const float4* xi = (const float4*)(x + (size_t)node * NC);
        const float4* xj = (const float4*)(x + (size_t)ng * NC);
#pragma unroll
        for (int kk = 0; kk < 16; kk++) {
          float4 a = xi[kk], bq = xj[kk];
          int kc8 = 8 + (kk >> 1);
          int pos = ((kc8 ^ (r & 7)) << 3) + ((kk & 1) << 2);
          unsigned short* d = &tile[r*128 + pos];
          d[0]=f2bf(bq.x-a.x); d[1]=f2bf(bq.y-a.y); d[2]=f2bf(bq.z-a.z); d[3]=f2bf(bq.w-a.w);
        }
      }
    }
    __syncthreads();
    // G1: 64x64 per wave, K=128
    f32x4 acc[4][4];
#pragma unroll
    for (int ri = 0; ri < 4; ri++)
#pragma unroll
      for (int ci = 0; ci < 4; ci++)
        acc[ri][ci] = (f32x4){0.f,0.f,0.f,0.f};
#pragma unroll
    for (int ks = 0; ks < 4; ks++) {
      short8 af[4], bf[4];
#pragma unroll
      for (int ri = 0; ri < 4; ri++) {
        int m = ri*16 + n16;
        int kc8 = (ks*4 + q) ^ (m & 7);
        af[ri] = *(const short8*)&tile[m*128 + kc8*8];
      }
#pragma unroll
      for (int ci = 0; ci < 4; ci++) {
        int col = cb + ci*16 + n16;
        bf[ci] = *(const short8*)(W1t + col*128 + ks*32 + q*8);
      }
#pragma unroll
      for (int ri = 0; ri < 4; ri++)
#pragma unroll
        for (int ci = 0; ci < 4; ci++)
          acc[ri][ci] = __builtin_amdgcn_mfma_f32_16x16x32_bf16(af[ri], bf[ci], acc[ri][ci], 0, 0, 0);
    }
    if (MODE == 0) {
#pragma unroll
      for (int ci = 0; ci < 4; ci++)
#pragma unroll
        for (int ri = 0; ri < 4; ri++)
#pragma unroll
          for (int r = 0; r < 4; r++) {
            float v = acc[ri][ci][r];
            ps[ci] += v; ps2[ci] += v*v;
          }
      continue;
    }
    if (MODE >= 1) {
      // bn1 affine + relu -> a-tile (same swizzled layout)
      __syncthreads();
#pragma unroll
      for (int ri = 0; ri < 4; ri++)
#pragma unroll
        for (int ci = 0; ci < 4; ci++) {
          int colL = cb + ci*16 + n16;
          int kc8 = colL >> 3;
#pragma unroll
          for (int r = 0; r < 4; r++) {
            float v = fmaxf(acc[ri][ci][r] * sc1[ci] + sh1[ci], 0.f);
            int rowL = ri*16 + q*4 + r;
            int pos = ((kc8 ^ (rowL & 7)) << 3) + (colL & 7);
            tile[rowL*128 + pos] = f2bf(v);
          }
        }
      __syncthreads();
      // G2
      f32x4 acc2[4][4];
#pragma unroll
      for (int ri = 0; ri < 4; ri++)
#pragma unroll
        for (int ci = 0; ci < 4; ci++)
          acc2[ri][ci] = (f32x4){0.f,0.f,0.f,0.f};
#pragma unroll
      for (int ks = 0; ks < 4; ks++) {
        short8 af[4], bf[4];
#pragma unroll
        for (int ri = 0; ri < 4; ri++) {
          int m = ri*16 + n16;
          int kc8 = (ks*4 + q) ^ (m & 7);
          af[ri] = *(const short8*)&tile[m*128 + kc8*8];
        }
#pragma unroll
        for (int ci = 0; ci < 4; ci++) {
          int col = cb + ci*16 + n16;
          bf[ci] = *(const short8*)(W2t + col*128 + ks*32 + q*8);
        }
#pragma unroll
        for (int ri = 0; ri < 4; ri++)
#pragma unroll
          for (int ci = 0; ci < 4; ci++)
            acc2[ri][ci] = __builtin_amdgcn_mfma_f32_16x16x32_bf16(af[ri], bf[ci], acc2[ri][ci], 0, 0, 0);
      }
      if (MODE == 1) {
#pragma unroll
        for (int ci = 0; ci < 4; ci++)
#pragma unroll
          for (int ri = 0; ri < 4; ri++)
#pragma unroll
            for (int r = 0; r < 4; r++) {
              float v = acc2[ri][ci][r];
              ps[ci] += v; ps2[ci] += v*v;
            }
      } else {
        // bn2 affine + relu + max over K (frag ri == one node: 16 rows = 16 k-samples)
#pragma unroll
        for (int ri = 0; ri < 4; ri++)
#pragma unroll
          for (int ci = 0; ci < 4; ci++) {
            int col = cb + ci*16 + n16;
            float vm = 0.f;  // relu output >= 0
#pragma unroll
            for (int r = 0; r < 4; r++) {
              float v = fmaxf(acc2[ri][ci][r] * sc2[ci] + sh2[ci], 0.f);
              vm = fmaxf(vm, v);
            }
            vm = fmaxf(vm, __shfl_xor(vm, 16, 64));
            vm = fmaxf(vm, __shfl_xor(vm, 32, 64));
            if (q == 0) {
              int node = (s0 >> 4) + ri;
              xout[(size_t)node*128 + col] = vm;
            }
          }
      }
    }
  }
  if (MODE <= 1) {
#pragma unroll
    for (int ci = 0; ci < 4; ci++) {
      float s = ps[ci], s2 = ps2[ci];
      s  += __shfl_xor(s, 16, 64);  s  += __shfl_xor(s, 32, 64);
      s2 += __shfl_xor(s2, 16, 64); s2 += __shfl_xor(s2, 32, 64);
      if (q == 0) {
        int col = cb + ci*16 + n16;
        atomicAdd(&stats[col], s);
        atomicAdd(&stats[128 + col], s2);
      }
    }
  }
}

// ---------------- finalize BN stats -> (scale, shift) ----------------
__global__ void finalize_kernel(const float* __restrict__ stats,
                                const float* __restrict__ g,
                                const float* __restrict__ be,
                                float* __restrict__ aff, float invcount) {
  int c = threadIdx.x;
  if (c < 128) {
    float mean = stats[c] * invcount;
    float var = stats[128 + c] * invcount - mean*mean;
    float scale = g[c] / sqrtf(var + EPSV);
    aff[c] = scale;
    aff[128 + c] = be[c] - mean * scale;
  }
}

// ---------------- final linear: [xs|xt] @ f_W -> d_out (pre-BN) + stats ----------------
__global__ __launch_bounds__(128) void final_pass(
    const float* __restrict__ xs,
    const float* __restrict__ xt,
    const unsigned short* __restrict__ fWt,
    float* __restrict__ gout,
    float* __restrict__ stats) {
  __shared__ unsigned short tile[64 * 256];
  int wave = threadIdx.x >> 6, lane = threadIdx.x & 63;
  int n16 = lane & 15, q = lane >> 4;
  int cb = wave * 64;
  int s0 = blockIdx.x * 64;
  {
    int r = threadIdx.x >> 1, half = threadIdx.x & 1;
    const float4* src = (const float4*)((half ? xt : xs) + (size_t)(s0 + r) * 128);
#pragma unroll
    for (int kk = 0; kk < 32; kk++) {
      float4 v = src[kk];
      int kc8 = half*16 + (kk >> 1);
      int pos = ((kc8 ^ (r & 7)) << 3) + ((kk & 1) << 2);
      unsigned short* d = &tile[r*256 + pos];
      d[0]=f2bf(v.x); d[1]=f2bf(v.y); d[2]=f2bf(v.z); d[3]=f2bf(v.w);
    }
  }
  __syncthreads();
  f32x4 acc[4][4];
#pragma unroll
  for (int ri = 0; ri < 4; ri++)
#pragma unroll
    for (int ci = 0; ci < 4; ci++)
      acc[ri][ci] = (f32x4){0.f,0.f,0.f,0.f};
#pragma unroll
  for (int ks = 0; ks < 8; ks++) {
    short8 af[4], bf[4];
#pragma unroll
    for (int ri = 0; ri < 4; ri++) {
      int m = ri*16 + n16;
      int kc8 = (ks*4 + q) ^ (m & 7);
      af[ri] = *(const short8*)&tile[m*256 + kc8*8];
    }
#pragma unroll
    for (int ci = 0; ci < 4; ci++) {
      int col = cb + ci*16 + n16;
      bf[ci] = *(const short8*)(fWt + col*256 + ks*32 + q*8);
    }
#pragma unroll
    for (int ri = 0; ri < 4; ri++)
#pragma unroll
      for (int ci = 0; ci < 4; ci++)
        acc[ri][ci] = __builtin_amdgcn_mfma_f32_16x16x32_bf16(af[ri], bf[ci], acc[ri][ci], 0, 0, 0);
  }
  float ps[4] = {0.f,0.f,0.f,0.f}, ps2[4] = {0.f,0.f,0.f,0.f};
#pragma unroll
  for (int ri = 0; ri < 4; ri++)
#pragma unroll
    for (int ci = 0; ci < 4; ci++) {
      int col = cb + ci*16 + n16;
#pragma unroll
      for (int r = 0; r < 4; r++) {
        float v = acc[ri][ci][r];
        int row = s0 + ri*16 + q*4 + r;
        gout[(size_t)row*128 + col] = v;
        ps[ci] += v; ps2[ci] += v*v;
      }
    }
#pragma unroll
  for (int ci = 0; ci < 4; ci++) {
    float s = ps[ci], s2 = ps2[ci];
    s  += __shfl_xor(s, 16, 64);  s  += __shfl_xor(s, 32, 64);
    s2 += __shfl_xor(s2, 16, 64); s2 += __shfl_xor(s2, 32, 64);
    if (q == 0) {
      int col = cb + ci*16 + n16;
      atomicAdd(&stats[col], s);
      atomicAdd(&stats[128 + col], s2);
    }
  }
}

__global__ void apply_bn_kernel(float* __restrict__ out, const float* __restrict__ aff) {
  int i = blockIdx.x * blockDim.x + threadIdx.x;
  if (i < NS*NH) {
    int c = i & 127;
    out[i] = fmaxf(out[i] * aff[c] + aff[128 + c], 0.f);
  }
}

extern "C" void kernel_launch(void* const* d_in, const int* in_sizes, int n_in,
                              void* d_out, int out_size, void* d_ws, size_t ws_size,
                              hipStream_t stream) {
  const float* x   = (const float*)d_in[0];
  const float* sW1 = (const float*)d_in[2];
  const float* sg1 = (const float*)d_in[4];
  const float* sbe1= (const float*)d_in[5];
  const float* sW2 = (const float*)d_in[6];
  const float* sg2 = (const float*)d_in[8];
  const float* sbe2= (const float*)d_in[9];
  const float* tW1 = (const float*)d_in[10];
  const float* tg1 = (const float*)d_in[12];
  const float* tbe1= (const float*)d_in[13];
  const float* tW2 = (const float*)d_in[14];
  const float* tg2 = (const float*)d_in[16];
  const float* tbe2= (const float*)d_in[17];
  const float* fW  = (const float*)d_in[18];
  const float* fg  = (const float*)d_in[20];
  const float* fbe = (const float*)d_in[21];
  float* out = (float*)d_out;

  char* w = (char*)d_ws;
  float* sq = (float*)w;                 w += (size_t)NS*4;
  int* nbr = (int*)w;                    w += (size_t)NSK*4;
  unsigned short* sW1t = (unsigned short*)w; w += 32768;
  unsigned short* sW2t = (unsigned short*)w; w += 32768;
  unsigned short* tW1t = (unsigned short*)w; w += 32768;
  unsigned short* tW2t = (unsigned short*)w; w += 32768;
  unsigned short* fWt  = (unsigned short*)w; w += 65536;
  float* stats = (float*)w;              w += 2560*4;
  float* xs = (float*)w;                 w += (size_t)NS*NH*4;
  float* xt = (float*)w;                 w += (size_t)NS*NH*4;

  float* st_s1 = stats;        float* af_s1 = stats + 256;
  float* st_s2 = stats + 512;  float* af_s2 = stats + 768;
  float* st_t1 = stats + 1024; float* af_t1 = stats + 1280;
  float* st_t2 = stats + 1536; float* af_t2 = stats + 1792;
  float* st_f  = stats + 2048; float* af_f  = stats + 2304;

  hipMemsetAsync(stats, 0, 2560*4, stream);
  prep_weights<<<(4*16384 + 128*256 + 255)/256, 256, 0, stream>>>(
      sW1, sW2, tW1, tW2, fW, sW1t, sW2t, tW1t, tW2t, fWt);
  sq_kernel<<<NS/256, 256, 0, stream>>>(x, sq);
  knn_kernel<<<NB*(NN/4), 256, 0, stream>>>(x, sq, nbr);

  const float inv1 = 1.f/(float)NSK, invf = 1.f/(float)NS;
  // s stream
  mlp_pass<0><<<1024,128,0,stream>>>(x, nbr, sW1t, sW2t, nullptr, nullptr, st_s1, nullptr);
  finalize_kernel<<<1,128,0,stream>>>(st_s1, sg1, sbe1, af_s1, inv1);
  mlp_pass<1><<<1024,128,0,stream>>>(x, nbr, sW1t, sW2t, af_s1, nullptr, st_s2, nullptr);
  finalize_kernel<<<1,128,0,stream>>>(st_s2, sg2, sbe2, af_s2, inv1);
  mlp_pass<2><<<1024,128,0,stream>>>(x, nbr, sW1t, sW2t, af_s1, af_s2, nullptr, xs);
  // t stream
  mlp_pass<0><<<1024,128,0,stream>>>(x, nbr, tW1t, tW2t, nullptr, nullptr, st_t1, nullptr);
  finalize_kernel<<<1,128,0,stream>>>(st_t1, tg1, tbe1, af_t1, inv1);
  mlp_pass<1><<<1024,128,0,stream>>>(x, nbr, tW1t, tW2t, af_t1, nullptr, st_t2, nullptr);
  finalize_kernel<<<1,128,0,stream>>>(st_t2, tg2, tbe2, af_t2, inv1);
  mlp_pass<2><<<1024,128,0,stream>>>(x, nbr, tW1t, tW2t, af_t1, af_t2, nullptr, xt);
  // final combine
  final_pass<<<NS/64, 128, 0, stream>>>(xs, xt, fWt, out, st_f);
  finalize_kernel<<<1,128,0,stream>>>(st_f, fg, fbe, af_f, invf);
  apply_bn_kernel<<<(NS*NH)/256, 256, 0, stream>>>(out, af_f);
}

// Round 2
// 1056.890 us; speedup vs baseline: 1.7757x; 1.7757x over previous
//
#include <hip/hip_runtime.h>
#include <hip/hip_bf16.h>
#include <stdint.h>

#define NB 16
#define NN 2048
#define NC 64
#define NH 128
#define NK 16
#define NS (NB*NN)
#define NSK (NS*NK)
#define EPSV 1e-5f

typedef __attribute__((ext_vector_type(8))) short short8;
typedef __attribute__((ext_vector_type(8))) _Float16 half8;
typedef __attribute__((ext_vector_type(8))) unsigned short ushort8;
typedef __attribute__((ext_vector_type(4))) float f32x4;

__device__ __forceinline__ unsigned short f2bf(float x) {
  union { float f; unsigned u; } v; v.f = x;
  unsigned r = v.u + 0x7fffu + ((v.u >> 16) & 1u);
  return (unsigned short)(r >> 16);
}

__device__ __forceinline__ unsigned orderf(float f) {
  unsigned u = __float_as_uint(f);
  return (u & 0x80000000u) ? ~u : (u | 0x80000000u);
}

__device__ __forceinline__ unsigned long long shfl_xor_u64(unsigned long long v, int m) {
  unsigned lo = (unsigned)(v & 0xffffffffull);
  unsigned hi = (unsigned)(v >> 32);
  lo = __shfl_xor(lo, m, 64);
  hi = __shfl_xor(hi, m, 64);
  return (((unsigned long long)hi) << 32) | lo;
}

// ---------------- prep: squared norms + split-fp16 (hi, lo) ----------------
__global__ void prep_x(const float* __restrict__ x, float* __restrict__ sq,
                       unsigned short* __restrict__ xh, unsigned short* __restrict__ xl) {
  int i = blockIdx.x * blockDim.x + threadIdx.x;
  if (i >= NS) return;
  const float4* x4 = (const float4*)(x + (size_t)i * NC);
  float s = 0.f;
#pragma unroll
  for (int k = 0; k < 8; k++) {
    float4 a = x4[2*k], b = x4[2*k+1];
    float f[8] = {a.x,a.y,a.z,a.w,b.x,b.y,b.z,b.w};
    ushort8 hv, lv;
#pragma unroll
    for (int j = 0; j < 8; j++) {
      float v = f[j];
      s += v*v;
      _Float16 h = (_Float16)v;
      float r = v - (float)h;
      _Float16 l = (_Float16)r;
      union { _Float16 ff; unsigned short u; } ch, cl;
      ch.ff = h; cl.ff = l;
      hv[j] = ch.u; lv[j] = cl.u;
    }
    *(ushort8*)(xh + (size_t)i*64 + k*8) = hv;
    *(ushort8*)(xl + (size_t)i*64 + k*8) = lv;
  }
  sq[i] = s;
}

// ---------------- kNN v2: split-fp16 MFMA Gram + fused top-16 ----------------
// grid: NB*32 workgroups (one per 64-row block), 256 threads (4 waves).
// wave w computes rows w*16..w*16+15 x 64-col chunks; top-16 per (row, col-quarter)
// in registers; final merge across the 4 quarters via shuffles.
__global__ __launch_bounds__(256) void knn2_kernel(const unsigned short* __restrict__ xh,
                                                   const unsigned short* __restrict__ xl,
                                                   const float* __restrict__ sq,
                                                   int* __restrict__ nbr) {
  __shared__ unsigned short rAh[64*64], rAl[64*64];
  __shared__ unsigned short cBh[64*64], cBl[64*64];
  __shared__ float gram[64*65];
  __shared__ float sqc[64];
  int b = blockIdx.x >> 5;
  int rb = blockIdx.x & 31;
  int w = threadIdx.x >> 6, lane = threadIdx.x & 63;
  int n16 = lane & 15, q = lane >> 4;
  int rowbase = b*NN + rb*64;

  // stage row block hi+lo, XOR-swizzled 16B chunks within each 128B row
  {
    int r = threadIdx.x >> 2;
    int c0 = (threadIdx.x & 3) * 2;
#pragma unroll
    for (int cc = 0; cc < 2; cc++) {
      int c = c0 + cc;
      int pos = (c ^ (r & 7)) * 8;
      *(ushort8*)&rAh[r*64 + pos] = *(const ushort8*)(xh + (size_t)(rowbase + r)*64 + c*8);
      *(ushort8*)&rAl[r*64 + pos] = *(const ushort8*)(xl + (size_t)(rowbase + r)*64 + c*8);
    }
  }
  __syncthreads();
  // hoist A fragments (rows fixed for whole kernel)
  half8 ah[2], al[2];
  int m = w*16 + n16;
#pragma unroll
  for (int ks = 0; ks < 2; ks++) {
    int pos = ((ks*4 + q) ^ (m & 7)) * 8;
    ah[ks] = *(const half8*)&rAh[m*64 + pos];
    al[ks] = *(const half8*)&rAl[m*64 + pos];
  }
  float sqr = sq[rowbase + m];

  unsigned long long keys[16];
#pragma unroll
  for (int i = 0; i < 16; i++) keys[i] = ~0ull;
  unsigned long long wkey = ~0ull;
  int wslot = 0;

  for (int ch = 0; ch < 32; ch++) {
    int colbase = b*NN + ch*64;
    __syncthreads();
    {
      int r = threadIdx.x >> 2;
      int c0 = (threadIdx.x & 3) * 2;
#pragma unroll
      for (int cc = 0; cc < 2; cc++) {
        int c = c0 + cc;
        int pos = (c ^ (r & 7)) * 8;
        *(ushort8*)&cBh[r*64 + pos] = *(const ushort8*)(xh + (size_t)(colbase + r)*64 + c*8);
        *(ushort8*)&cBl[r*64 + pos] = *(const ushort8*)(xl + (size_t)(colbase + r)*64 + c*8);
      }
      if (threadIdx.x < 64) sqc[threadIdx.x] = sq[colbase + threadIdx.x];
    }
    __syncthreads();
    // Gram strip 16x64 per wave: 3-product split-fp16
    f32x4 acc[4];
#pragma unroll
    for (int ci = 0; ci < 4; ci++) acc[ci] = (f32x4){0.f,0.f,0.f,0.f};
#pragma unroll
    for (int ks = 0; ks < 2; ks++) {
#pragma unroll
      for (int ci = 0; ci < 4; ci++) {
        int n = ci*16 + n16;
        int pos = ((ks*4 + q) ^ (n & 7)) * 8;
        half8 bh = *(const half8*)&cBh[n*64 + pos];
        half8 bl = *(const half8*)&cBl[n*64 + pos];
        acc[ci] = __builtin_amdgcn_mfma_f32_16x16x32_f16(ah[ks], bh, acc[ci], 0, 0, 0);
        acc[ci] = __builtin_amdgcn_mfma_f32_16x16x32_f16(al[ks], bh, acc[ci], 0, 0, 0);
        acc[ci] = __builtin_amdgcn_mfma_f32_16x16x32_f16(ah[ks], bl, acc[ci], 0, 0, 0);
      }
    }
    // write gram strip (C layout: col=ci*16+n16, row=w*16+q*4+r), stride 65
#pragma unroll
    for (int ci = 0; ci < 4; ci++)
#pragma unroll
      for (int r = 0; r < 4; r++)
        gram[(w*16 + q*4 + r)*65 + ci*16 + n16] = acc[ci][r];
    __syncthreads();
    // scan: lane owns row w*16+n16, cols q*16..q*16+15
    const float* gp = &gram[(size_t)(w*16 + n16)*65 + q*16];
#pragma unroll
    for (int i = 0; i < 16; i++) {
      float g = gp[i];
      float d2 = sqr + sqc[q*16 + i] - 2.f*g;
      unsigned long long key = ((unsigned long long)orderf(d2) << 32) |
                               (unsigned)(colbase + q*16 + i);
      if (key < wkey) {
        keys[wslot] = key;
        wkey = keys[0]; wslot = 0;
#pragma unroll
        for (int ii = 1; ii < 16; ii++) if (keys[ii] > wkey) { wkey = keys[ii]; wslot = ii; }
      }
    }
  }
  // merge the 4 col-quarter lists per row (lanes n16, n16+16, n16+32, n16+48)
  for (int j = 0; j < NK; j++) {
    unsigned long long mk = keys[0];
#pragma unroll
    for (int i = 1; i < 16; i++) mk = (keys[i] < mk) ? keys[i] : mk;
    unsigned long long o = shfl_xor_u64(mk, 16); mk = (o < mk) ? o : mk;
    o = shfl_xor_u64(mk, 32); mk = (o < mk) ? o : mk;
#pragma unroll
    for (int i = 0; i < 16; i++) if (keys[i] == mk) keys[i] = ~0ull;
    if (q == 0) nbr[(size_t)(rowbase + m)*NK + j] = (int)(mk & 0xffffffffu);
  }
}

// ---------------- weight prep: transpose + bf16 ----------------
__global__ void prep_weights(const float* __restrict__ sW1, const float* __restrict__ sW2,
                             const float* __restrict__ tW1, const float* __restrict__ tW2,
                             const float* __restrict__ fW,
                             unsigned short* __restrict__ sW1t, unsigned short* __restrict__ sW2t,
                             unsigned short* __restrict__ tW1t, unsigned short* __restrict__ tW2t,
                             unsigned short* __restrict__ fWt) {
  int i = blockIdx.x * blockDim.x + threadIdx.x;
  if (i < 4*16384) {
    int mi = i >> 14, e = i & 16383;
    int h = e >> 7, k = e & 127;
    const float* src = (mi==0) ? sW1 : (mi==1) ? sW2 : (mi==2) ? tW1 : tW2;
    unsigned short* dst = (mi==0) ? sW1t : (mi==1) ? sW2t : (mi==2) ? tW1t : tW2t;
    dst[h*128 + k] = f2bf(src[k*128 + h]);
  } else {
    int e = i - 4*16384;
    if (e < 128*256) {
      int h = e >> 8, k = e & 255;
      fWt[h*256 + k] = f2bf(fW[k*128 + h]);
    }
  }
}

// ---------------- fused EdgeConv MLP pass ----------------
// MODE 0: GEMM1 -> stats(h1)
// MODE 1: GEMM1 -> bn1+relu -> GEMM2 -> stats(h2)
// MODE 2: GEMM1 -> bn1+relu -> GEMM2 -> bn2+relu -> max over K -> xout
template<int MODE>
__global__ __launch_bounds__(128) void mlp_pass(
    const float* __restrict__ x,
    const int* __restrict__ nbr,
    const unsigned short* __restrict__ W1t,
    const unsigned short* __restrict__ W2t,
    const float* __restrict__ aff1,
    const float* __restrict__ aff2,
    float* __restrict__ stats,
    float* __restrict__ xout) {
  __shared__ unsigned short tile[64 * 128];
  int wave = threadIdx.x >> 6;
  int lane = threadIdx.x & 63;
  int n16 = lane & 15;
  int q = lane >> 4;
  int cb = wave * 64;

  float sc1[4], sh1[4], sc2[4], sh2[4];
  if (MODE >= 1) {
#pragma unroll
    for (int ci = 0; ci < 4; ci++) {
      int col = cb + ci*16 + n16;
      sc1[ci] = aff1[col]; sh1[ci] = aff1[128 + col];
    }
  }
  if (MODE == 2) {
#pragma unroll
    for (int ci = 0; ci < 4; ci++) {
      int col = cb + ci*16 + n16;
      sc2[ci] = aff2[col]; sh2[ci] = aff2[128 + col];
    }
  }
  float ps[4] = {0.f,0.f,0.f,0.f}, ps2[4] = {0.f,0.f,0.f,0.f};

  for (int it = 0; it < 8; it++) {
    int tileIdx = blockIdx.x * 8 + it;
    int s0 = tileIdx * 64;
    __syncthreads();
    {
      int r = threadIdx.x >> 1, half = threadIdx.x & 1;
      int s = s0 + r;
      int node = s >> 4;
      if (half == 0) {
        const float4* xp = (const float4*)(x + (size_t)node * NC);
#pragma unroll
        for (int kk = 0; kk < 16; kk++) {
          float4 v = xp[kk];
          int kc8 = kk >> 1;
          int pos = ((kc8 ^ (r & 7)) << 3) + ((kk & 1) << 2);
          unsigned short* d = &tile[r*128 + pos];
          d[0]=f2bf(v.x); d[1]=f2bf(v.y); d[2]=f2bf(v.z); d[3]=f2bf(v.w);
        }
      } else {
        int ng = nbr[s];
        const float4* xi = (const float4*)(x + (size_t)node * NC);
        const float4* xj = (const float4*)(x + (size_t)ng * NC);
#pragma unroll
        for (int kk = 0; kk < 16; kk++) {
          float4 a = xi[kk], bq = xj[kk];
          int kc8 = 8 + (kk >> 1);
          int pos = ((kc8 ^ (r & 7)) << 3) + ((kk & 1) << 2);
          unsigned short* d = &tile[r*128 + pos];
          d[0]=f2bf(bq.x-a.x); d[1]=f2bf(bq.y-a.y); d[2]=f2bf(bq.z-a.z); d[3]=f2bf(bq.w-a.w);
        }
      }
    }
    __syncthreads();
    f32x4 acc[4][4];
#pragma unroll
    for (int ri = 0; ri < 4; ri++)
#pragma unroll
      for (int ci = 0; ci < 4; ci++)
        acc[ri][ci] = (f32x4){0.f,0.f,0.f,0.f};
#pragma unroll
    for (int ks = 0; ks < 4; ks++) {
      short8 af[4], bf[4];
#pragma unroll
      for (int ri = 0; ri < 4; ri++) {
        int mm = ri*16 + n16;
        int kc8 = (ks*4 + q) ^ (mm & 7);
        af[ri] = *(const short8*)&tile[mm*128 + kc8*8];
      }
#pragma unroll
      for (int ci = 0; ci < 4; ci++) {
        int col = cb + ci*16 + n16;
        bf[ci] = *(const short8*)(W1t + col*128 + ks*32 + q*8);
      }
#pragma unroll
      for (int ri = 0; ri < 4; ri++)
#pragma unroll
        for (int ci = 0; ci < 4; ci++)
          acc[ri][ci] = __builtin_amdgcn_mfma_f32_16x16x32_bf16(af[ri], bf[ci], acc[ri][ci], 0, 0, 0);
    }
    if (MODE == 0) {
#pragma unroll
      for (int ci = 0; ci < 4; ci++)
#pragma unroll
        for (int ri = 0; ri < 4; ri++)
#pragma unroll
          for (int r = 0; r < 4; r++) {
            float v = acc[ri][ci][r];
            ps[ci] += v; ps2[ci] += v*v;
          }
      continue;
    }
    if (MODE >= 1) {
      __syncthreads();
#pragma unroll
      for (int ri = 0; ri < 4; ri++)
#pragma unroll
        for (int ci = 0; ci < 4; ci++) {
          int colL = cb + ci*16 + n16;
          int kc8 = colL >> 3;
#pragma unroll
          for (int r = 0; r < 4; r++) {
            float v = fmaxf(acc[ri][ci][r] * sc1[ci] + sh1[ci], 0.f);
            int rowL = ri*16 + q*4 + r;
            int pos = ((kc8 ^ (rowL & 7)) << 3) + (colL & 7);
            tile[rowL*128 + pos] = f2bf(v);
          }
        }
      __syncthreads();
      f32x4 acc2[4][4];
#pragma unroll
      for (int ri = 0; ri < 4; ri++)
#pragma unroll
        for (int ci = 0; ci < 4; ci++)
          acc2[ri][ci] = (f32x4){0.f,0.f,0.f,0.f};
#pragma unroll
      for (int ks = 0; ks < 4; ks++) {
        short8 af[4], bf[4];
#pragma unroll
        for (int ri = 0; ri < 4; ri++) {
          int mm = ri*16 + n16;
          int kc8 = (ks*4 + q) ^ (mm & 7);
          af[ri] = *(const short8*)&tile[mm*128 + kc8*8];
        }
#pragma unroll
        for (int ci = 0; ci < 4; ci++) {
          int col = cb + ci*16 + n16;
          bf[ci] = *(const short8*)(W2t + col*128 + ks*32 + q*8);
        }
#pragma unroll
        for (int ri = 0; ri < 4; ri++)
#pragma unroll
          for (int ci = 0; ci < 4; ci++)
            acc2[ri][ci] = __builtin_amdgcn_mfma_f32_16x16x32_bf16(af[ri], bf[ci], acc2[ri][ci], 0, 0, 0);
      }
      if (MODE == 1) {
#pragma unroll
        for (int ci = 0; ci < 4; ci++)
#pragma unroll
          for (int ri = 0; ri < 4; ri++)
#pragma unroll
            for (int r = 0; r < 4; r++) {
              float v = acc2[ri][ci][r];
              ps[ci] += v; ps2[ci] += v*v;
            }
      } else {
#pragma unroll
        for (int ri = 0; ri < 4; ri++)
#pragma unroll
          for (int ci = 0; ci < 4; ci++) {
            int col = cb + ci*16 + n16;
            float vm = 0.f;
#pragma unroll
            for (int r = 0; r < 4; r++) {
              float v = fmaxf(acc2[ri][ci][r] * sc2[ci] + sh2[ci], 0.f);
              vm = fmaxf(vm, v);
            }
            vm = fmaxf(vm, __shfl_xor(vm, 16, 64));
            vm = fmaxf(vm, __shfl_xor(vm, 32, 64));
            if (q == 0) {
              int node = (s0 >> 4) + ri;
              xout[(size_t)node*128 + col] = vm;
            }
          }
      }
    }
  }
  if (MODE <= 1) {
#pragma unroll
    for (int ci = 0; ci < 4; ci++) {
      float s = ps[ci], s2 = ps2[ci];
      s  += __shfl_xor(s, 16, 64);  s  += __shfl_xor(s, 32, 64);
      s2 += __shfl_xor(s2, 16, 64); s2 += __shfl_xor(s2, 32, 64);
      if (q == 0) {
        int col = cb + ci*16 + n16;
        atomicAdd(&stats[col], s);
        atomicAdd(&stats[128 + col], s2);
      }
    }
  }
}

// ---------------- finalize BN stats -> (scale, shift) ----------------
__global__ void finalize_kernel(const float* __restrict__ stats,
                                const float* __restrict__ g,
                                const float* __restrict__ be,
                                float* __restrict__ aff, float invcount) {
  int c = threadIdx.x;
  if (c < 128) {
    float mean = stats[c] * invcount;
    float var = stats[128 + c] * invcount - mean*mean;
    float scale = g[c] / sqrtf(var + EPSV);
    aff[c] = scale;
    aff[128 + c] = be[c] - mean * scale;
  }
}

// ---------------- final linear ----------------
__global__ __launch_bounds__(128) void final_pass(
    const float* __restrict__ xs,
    const float* __restrict__ xt,
    const unsigned short* __restrict__ fWt,
    float* __restrict__ gout,
    float* __restrict__ stats) {
  __shared__ unsigned short tile[64 * 256];
  int wave = threadIdx.x >> 6, lane = threadIdx.x & 63;
  int n16 = lane & 15, q = lane >> 4;
  int cb = wave * 64;
  int s0 = blockIdx.x * 64;
  {
    int r = threadIdx.x >> 1, half = threadIdx.x & 1;
    const float4* src = (const float4*)((half ? xt : xs) + (size_t)(s0 + r) * 128);
#pragma unroll
    for (int kk = 0; kk < 32; kk++) {
      float4 v = src[kk];
      int kc8 = half*16 + (kk >> 1);
      int pos = ((kc8 ^ (r & 7)) << 3) + ((kk & 1) << 2);
      unsigned short* d = &tile[r*256 + pos];
      d[0]=f2bf(v.x); d[1]=f2bf(v.y); d[2]=f2bf(v.z); d[3]=f2bf(v.w);
    }
  }
  __syncthreads();
  f32x4 acc[4][4];
#pragma unroll
  for (int ri = 0; ri < 4; ri++)
#pragma unroll
    for (int ci = 0; ci < 4; ci++)
      acc[ri][ci] = (f32x4){0.f,0.f,0.f,0.f};
#pragma unroll
  for (int ks = 0; ks < 8; ks++) {
    short8 af[4], bf[4];
#pragma unroll
    for (int ri = 0; ri < 4; ri++) {
      int mm = ri*16 + n16;
      int kc8 = (ks*4 + q) ^ (mm & 7);
      af[ri] = *(const short8*)&tile[mm*256 + kc8*8];
    }
#pragma unroll
    for (int ci = 0; ci < 4; ci++) {
      int col = cb + ci*16 + n16;
      bf[ci] = *(const short8*)(fWt + col*256 + ks*32 + q*8);
    }
#pragma unroll
    for (int ri = 0; ri < 4; ri++)
#pragma unroll
      for (int ci = 0; ci < 4; ci++)
        acc[ri][ci] = __builtin_amdgcn_mfma_f32_16x16x32_bf16(af[ri], bf[ci], acc[ri][ci], 0, 0, 0);
  }
  float ps[4] = {0.f,0.f,0.f,0.f}, ps2[4] = {0.f,0.f,0.f,0.f};
#pragma unroll
  for (int ri = 0; ri < 4; ri++)
#pragma unroll
    for (int ci = 0; ci < 4; ci++) {
      int col = cb + ci*16 + n16;
#pragma unroll
      for (int r = 0; r < 4; r++) {
        float v = acc[ri][ci][r];
        int row = s0 + ri*16 + q*4 + r;
        gout[(size_t)row*128 + col] = v;
        ps[ci] += v; ps2[ci] += v*v;
      }
    }
#pragma unroll
  for (int ci = 0; ci < 4; ci++) {
    float s = ps[ci], s2 = ps2[ci];
    s  += __shfl_xor(s, 16, 64);  s  += __shfl_xor(s, 32, 64);
    s2 += __shfl_xor(s2, 16, 64); s2 += __shfl_xor(s2, 32, 64);
    if (q == 0) {
      int col = cb + ci*16 + n16;
      atomicAdd(&stats[col], s);
      atomicAdd(&stats[128 + col], s2);
    }
  }
}

__global__ void apply_bn_kernel(float* __restrict__ out, const float* __restrict__ aff) {
  int i = blockIdx.x * blockDim.x + threadIdx.x;
  if (i < NS*NH) {
    int c = i & 127;
    out[i] = fmaxf(out[i] * aff[c] + aff[128 + c], 0.f);
  }
}

extern "C" void kernel_launch(void* const* d_in, const int* in_sizes, int n_in,
                              void* d_out, int out_size, void* d_ws, size_t ws_size,
                              hipStream_t stream) {
  const float* x   = (const float*)d_in[0];
  const float* sW1 = (const float*)d_in[2];
  const float* sg1 = (const float*)d_in[4];
  const float* sbe1= (const float*)d_in[5];
  const float* sW2 = (const float*)d_in[6];
  const float* sg2 = (const float*)d_in[8];
  const float* sbe2= (const float*)d_in[9];
  const float* tW1 = (const float*)d_in[10];
  const float* tg1 = (const float*)d_in[12];
  const float* tbe1= (const float*)d_in[13];
  const float* tW2 = (const float*)d_in[14];
  const float* tg2 = (const float*)d_in[16];
  const float* tbe2= (const float*)d_in[17];
  const float* fW  = (const float*)d_in[18];
  const float* fg  = (const float*)d_in[20];
  const float* fbe = (const float*)d_in[21];
  float* out = (float*)d_out;

  char* w = (char*)d_ws;
  float* sq = (float*)w;                 w += (size_t)NS*4;
  int* nbr = (int*)w;                    w += (size_t)NSK*4;
  unsigned short* sW1t = (unsigned short*)w; w += 32768;
  unsigned short* sW2t = (unsigned short*)w; w += 32768;
  unsigned short* tW1t = (unsigned short*)w; w += 32768;
  unsigned short* tW2t = (unsigned short*)w; w += 32768;
  unsigned short* fWt  = (unsigned short*)w; w += 65536;
  float* stats = (float*)w;              w += 2560*4;
  float* xs = (float*)w;                 w += (size_t)NS*NH*4;
  float* xt = (float*)w;                 w += (size_t)NS*NH*4;
  unsigned short* xh = (unsigned short*)w; w += (size_t)NS*64*2;
  unsigned short* xl = (unsigned short*)w; w += (size_t)NS*64*2;

  float* st_s1 = stats;        float* af_s1 = stats + 256;
  float* st_s2 = stats + 512;  float* af_s2 = stats + 768;
  float* st_t1 = stats + 1024; float* af_t1 = stats + 1280;
  float* st_t2 = stats + 1536; float* af_t2 = stats + 1792;
  float* st_f  = stats + 2048; float* af_f  = stats + 2304;

  hipMemsetAsync(stats, 0, 2560*4, stream);
  prep_weights<<<(4*16384 + 128*256 + 255)/256, 256, 0, stream>>>(
      sW1, sW2, tW1, tW2, fW, sW1t, sW2t, tW1t, tW2t, fWt);
  prep_x<<<NS/256, 256, 0, stream>>>(x, sq, xh, xl);
  knn2_kernel<<<NB*32, 256, 0, stream>>>(xh, xl, sq, nbr);

  const float inv1 = 1.f/(float)NSK, invf = 1.f/(float)NS;
  // s stream
  mlp_pass<0><<<1024,128,0,stream>>>(x, nbr, sW1t, sW2t, nullptr, nullptr, st_s1, nullptr);
  finalize_kernel<<<1,128,0,stream>>>(st_s1, sg1, sbe1, af_s1, inv1);
  mlp_pass<1><<<1024,128,0,stream>>>(x, nbr, sW1t, sW2t, af_s1, nullptr, st_s2, nullptr);
  finalize_kernel<<<1,128,0,stream>>>(st_s2, sg2, sbe2, af_s2, inv1);
  mlp_pass<2><<<1024,128,0,stream>>>(x, nbr, sW1t, sW2t, af_s1, af_s2, nullptr, xs);
  // t stream
  mlp_pass<0><<<1024,128,0,stream>>>(x, nbr, tW1t, tW2t, nullptr, nullptr, st_t1, nullptr);
  finalize_kernel<<<1,128,0,stream>>>(st_t1, tg1, tbe1, af_t1, inv1);
  mlp_pass<1><<<1024,128,0,stream>>>(x, nbr, tW1t, tW2t, af_t1, nullptr, st_t2, nullptr);
  finalize_kernel<<<1,128,0,stream>>>(st_t2, tg2, tbe2, af_t2, inv1);
  mlp_pass<2><<<1024,128,0,stream>>>(x, nbr, tW1t, tW2t, af_t1, af_t2, nullptr, xt);
  // final combine
  final_pass<<<NS/64, 128, 0, stream>>>(xs, xt, fWt, out, st_f);
  finalize_kernel<<<1,128,0,stream>>>(st_f, fg, fbe, af_f, invf);
  apply_bn_kernel<<<(NS*NH)/256, 256, 0, stream>>>(out, af_f);
}

// Round 3
// 1056.640 us; speedup vs baseline: 1.7762x; 1.0002x over previous
//
#include <hip/hip_runtime.h>
#include <hip/hip_bf16.h>
#include <stdint.h>

#define NB 16
#define NN 2048
#define NC 64
#define NH 128
#define NK 16
#define NS (NB*NN)
#define NSK (NS*NK)
#define EPSV 1e-5f

typedef __attribute__((ext_vector_type(8))) short short8;
typedef __attribute__((ext_vector_type(8))) _Float16 half8;
typedef __attribute__((ext_vector_type(8))) unsigned short ushort8;
typedef __attribute__((ext_vector_type(4))) float f32x4;

__device__ __forceinline__ unsigned short f2bf(float x) {
  union { float f; unsigned u; } v; v.f = x;
  unsigned r = v.u + 0x7fffu + ((v.u >> 16) & 1u);
  return (unsigned short)(r >> 16);
}

__device__ __forceinline__ unsigned orderf(float f) {
  unsigned u = __float_as_uint(f);
  return u ^ ((unsigned)((int)u >> 31) | 0x80000000u);
}

__device__ __forceinline__ unsigned long long shfl_xor_u64(unsigned long long v, int m) {
  unsigned lo = (unsigned)(v & 0xffffffffull);
  unsigned hi = (unsigned)(v >> 32);
  lo = __shfl_xor(lo, m, 64);
  hi = __shfl_xor(hi, m, 64);
  return (((unsigned long long)hi) << 32) | lo;
}

// ---------------- prep: squared norms + split-fp16 (hi, lo) ----------------
__global__ void prep_x(const float* __restrict__ x, float* __restrict__ sq,
                       unsigned short* __restrict__ xh, unsigned short* __restrict__ xl) {
  int i = blockIdx.x * blockDim.x + threadIdx.x;
  if (i >= NS) return;
  const float4* x4 = (const float4*)(x + (size_t)i * NC);
  float s = 0.f;
#pragma unroll
  for (int k = 0; k < 8; k++) {
    float4 a = x4[2*k], b = x4[2*k+1];
    float f[8] = {a.x,a.y,a.z,a.w,b.x,b.y,b.z,b.w};
    ushort8 hv, lv;
#pragma unroll
    for (int j = 0; j < 8; j++) {
      float v = f[j];
      s += v*v;
      _Float16 h = (_Float16)v;
      float r = v - (float)h;
      _Float16 l = (_Float16)r;
      union { _Float16 ff; unsigned short u; } ch, cl;
      ch.ff = h; cl.ff = l;
      hv[j] = ch.u; lv[j] = cl.u;
    }
    *(ushort8*)(xh + (size_t)i*64 + k*8) = hv;
    *(ushort8*)(xl + (size_t)i*64 + k*8) = lv;
  }
  sq[i] = s;
}

// ---------------- kNN v3: MFMA Gram + batched-filter sorted-insert top-16 ----------------
__global__ __launch_bounds__(256) void knn3_kernel(const unsigned short* __restrict__ xh,
                                                   const unsigned short* __restrict__ xl,
                                                   const float* __restrict__ sq,
                                                   int* __restrict__ nbr) {
  __shared__ unsigned short rAh[64*64], rAl[64*64];
  __shared__ unsigned short cBh[64*64], cBl[64*64];
  __shared__ float gram[64*68];
  __shared__ float sqc[64];
  int b = blockIdx.x >> 5;
  int rb = blockIdx.x & 31;
  int w = threadIdx.x >> 6, lane = threadIdx.x & 63;
  int n16 = lane & 15, q = lane >> 4;
  int rowbase = b*NN + rb*64;

  // stage row block hi+lo, XOR-swizzled 16B chunks
  {
    int r = threadIdx.x >> 2;
    int c0 = (threadIdx.x & 3) * 2;
#pragma unroll
    for (int cc = 0; cc < 2; cc++) {
      int c = c0 + cc;
      int pos = (c ^ (r & 7)) * 8;
      *(ushort8*)&rAh[r*64 + pos] = *(const ushort8*)(xh + (size_t)(rowbase + r)*64 + c*8);
      *(ushort8*)&rAl[r*64 + pos] = *(const ushort8*)(xl + (size_t)(rowbase + r)*64 + c*8);
    }
  }
  __syncthreads();
  half8 ah[2], al[2];
  int m = w*16 + n16;
#pragma unroll
  for (int ks = 0; ks < 2; ks++) {
    int pos = ((ks*4 + q) ^ (m & 7)) * 8;
    ah[ks] = *(const half8*)&rAh[m*64 + pos];
    al[ks] = *(const half8*)&rAl[m*64 + pos];
  }
  float sqr = sq[rowbase + m];

  unsigned long long keys[16];   // sorted ascending; keys[15] = current worst
#pragma unroll
  for (int i = 0; i < 16; i++) keys[i] = ~0ull;
  unsigned whi = 0xffffffffu;    // high-32 (orderf d2) of worst

  for (int ch = 0; ch < 32; ch++) {
    int colbase = b*NN + ch*64;
    __syncthreads();
    {
      int r = threadIdx.x >> 2;
      int c0 = (threadIdx.x & 3) * 2;
#pragma unroll
      for (int cc = 0; cc < 2; cc++) {
        int c = c0 + cc;
        int pos = (c ^ (r & 7)) * 8;
        *(ushort8*)&cBh[r*64 + pos] = *(const ushort8*)(xh + (size_t)(colbase + r)*64 + c*8);
        *(ushort8*)&cBl[r*64 + pos] = *(const ushort8*)(xl + (size_t)(colbase + r)*64 + c*8);
      }
      if (threadIdx.x < 64) sqc[threadIdx.x] = sq[colbase + threadIdx.x];
    }
    __syncthreads();
    // Gram strip 16x64 per wave: 3-product split-fp16
    f32x4 acc[4];
#pragma unroll
    for (int ci = 0; ci < 4; ci++) acc[ci] = (f32x4){0.f,0.f,0.f,0.f};
#pragma unroll
    for (int ks = 0; ks < 2; ks++) {
#pragma unroll
      for (int ci = 0; ci < 4; ci++) {
        int n = ci*16 + n16;
        int pos = ((ks*4 + q) ^ (n & 7)) * 8;
        half8 bh = *(const half8*)&cBh[n*64 + pos];
        half8 bl = *(const half8*)&cBl[n*64 + pos];
        acc[ci] = __builtin_amdgcn_mfma_f32_16x16x32_f16(ah[ks], bh, acc[ci], 0, 0, 0);
        acc[ci] = __builtin_amdgcn_mfma_f32_16x16x32_f16(al[ks], bh, acc[ci], 0, 0, 0);
        acc[ci] = __builtin_amdgcn_mfma_f32_16x16x32_f16(ah[ks], bl, acc[ci], 0, 0, 0);
      }
    }
#pragma unroll
    for (int ci = 0; ci < 4; ci++)
#pragma unroll
      for (int r = 0; r < 4; r++)
        gram[(w*16 + q*4 + r)*68 + ci*16 + n16] = acc[ci][r];
    __syncthreads();
    // scan: lane owns row w*16+n16, cols q*16..q*16+15
    const float* gp = &gram[(size_t)(w*16 + n16)*68 + q*16];
    const float* sc = &sqc[q*16];
    unsigned mask = 0;
#pragma unroll
    for (int i4 = 0; i4 < 4; i4++) {
      float4 g4 = *(const float4*)(gp + i4*4);
      float4 s4 = *(const float4*)(sc + i4*4);
      float d0 = fmaf(-2.f, g4.x, sqr + s4.x);
      float d1 = fmaf(-2.f, g4.y, sqr + s4.y);
      float d2 = fmaf(-2.f, g4.z, sqr + s4.z);
      float d3 = fmaf(-2.f, g4.w, sqr + s4.w);
      if (orderf(d0) <= whi) mask |= 1u << (i4*4+0);
      if (orderf(d1) <= whi) mask |= 1u << (i4*4+1);
      if (orderf(d2) <= whi) mask |= 1u << (i4*4+2);
      if (orderf(d3) <= whi) mask |= 1u << (i4*4+3);
    }
    while (mask) {
      int i = __builtin_ctz(mask);
      mask &= mask - 1;
      float g = gp[i];
      float dd = fmaf(-2.f, g, sqr + sc[i]);
      unsigned long long key = ((unsigned long long)orderf(dd) << 32) |
                               (unsigned)(colbase + q*16 + i);
      // static sorted insert (compare-exchange chain)
#pragma unroll
      for (int j = 0; j < 16; j++) {
        bool cl = key < keys[j];
        unsigned long long lo = cl ? key : keys[j];
        key = cl ? keys[j] : key;
        keys[j] = lo;
      }
      whi = (unsigned)(keys[15] >> 32);
    }
  }
  // merge the 4 col-quarter lists per row
  for (int j = 0; j < NK; j++) {
    unsigned long long mk = keys[0];
#pragma unroll
    for (int i = 1; i < 16; i++) mk = (keys[i] < mk) ? keys[i] : mk;
    unsigned long long o = shfl_xor_u64(mk, 16); mk = (o < mk) ? o : mk;
    o = shfl_xor_u64(mk, 32); mk = (o < mk) ? o : mk;
#pragma unroll
    for (int i = 0; i < 16; i++) if (keys[i] == mk) keys[i] = ~0ull;
    if (q == 0) nbr[(size_t)(rowbase + m)*NK + j] = (int)(mk & 0xffffffffu);
  }
}

// ---------------- weight prep ----------------
__global__ void prep_weights(const float* __restrict__ sW1, const float* __restrict__ sW2,
                             const float* __restrict__ tW1, const float* __restrict__ tW2,
                             const float* __restrict__ fW,
                             unsigned short* __restrict__ sW1t, unsigned short* __restrict__ sW2t,
                             unsigned short* __restrict__ tW1t, unsigned short* __restrict__ tW2t,
                             unsigned short* __restrict__ fWt) {
  int i = blockIdx.x * blockDim.x + threadIdx.x;
  if (i < 4*16384) {
    int mi = i >> 14, e = i & 16383;
    int h = e >> 7, k = e & 127;
    const float* src = (mi==0) ? sW1 : (mi==1) ? sW2 : (mi==2) ? tW1 : tW2;
    unsigned short* dst = (mi==0) ? sW1t : (mi==1) ? sW2t : (mi==2) ? tW1t : tW2t;
    dst[h*128 + k] = f2bf(src[k*128 + h]);
  } else {
    int e = i - 4*16384;
    if (e < 128*256) {
      int h = e >> 8, k = e & 255;
      fWt[h*256 + k] = f2bf(fW[k*128 + h]);
    }
  }
}

// ---------------- dual-stream fused EdgeConv MLP pass ----------------
// MODE 0: GEMM1 -> stats(h1) for both streams
// MODE 1: GEMM1 -> bn1+relu -> GEMM2 -> stats(h2) for both streams
// MODE 2: ... -> bn2+relu -> max over K -> xout for both streams
template<int MODE>
__global__ __launch_bounds__(128, 2) void mlp_dual(
    const float* __restrict__ x,
    const int* __restrict__ nbr,
    const unsigned short* __restrict__ sW1t, const unsigned short* __restrict__ sW2t,
    const unsigned short* __restrict__ tW1t, const unsigned short* __restrict__ tW2t,
    const float* __restrict__ affS1, const float* __restrict__ affS2,
    const float* __restrict__ affT1, const float* __restrict__ affT2,
    float* __restrict__ statS, float* __restrict__ statT,
    float* __restrict__ xoutS, float* __restrict__ xoutT) {
  __shared__ unsigned short etile[64 * 128];
  __shared__ unsigned short atile[(MODE >= 1) ? 64 * 128 : 64];
  int wave = threadIdx.x >> 6;
  int lane = threadIdx.x & 63;
  int n16 = lane & 15;
  int q = lane >> 4;
  int cb = wave * 64;

  float s1S[4], h1S[4], s2S[4], h2S[4];
  float s1T[4], h1T[4], s2T[4], h2T[4];
  if (MODE >= 1) {
#pragma unroll
    for (int ci = 0; ci < 4; ci++) {
      int col = cb + ci*16 + n16;
      s1S[ci] = affS1[col]; h1S[ci] = affS1[128 + col];
      s1T[ci] = affT1[col]; h1T[ci] = affT1[128 + col];
    }
  }
  if (MODE == 2) {
#pragma unroll
    for (int ci = 0; ci < 4; ci++) {
      int col = cb + ci*16 + n16;
      s2S[ci] = affS2[col]; h2S[ci] = affS2[128 + col];
      s2T[ci] = affT2[col]; h2T[ci] = affT2[128 + col];
    }
  }
  float psS[4] = {0,0,0,0}, ps2S[4] = {0,0,0,0};
  float psT[4] = {0,0,0,0}, ps2T[4] = {0,0,0,0};

  for (int it = 0; it < 8; it++) {
    int tileIdx = blockIdx.x * 8 + it;
    int s0 = tileIdx * 64;
    __syncthreads();
    // stage e-tile once (shared by both streams)
    {
      int r = threadIdx.x >> 1, half = threadIdx.x & 1;
      int s = s0 + r;
      int node = s >> 4;
      if (half == 0) {
        const float4* xp = (const float4*)(x + (size_t)node * NC);
#pragma unroll
        for (int kk = 0; kk < 16; kk++) {
          float4 v = xp[kk];
          int kc8 = kk >> 1;
          int pos = ((kc8 ^ (r & 7)) << 3) + ((kk & 1) << 2);
          unsigned short* d = &etile[r*128 + pos];
          d[0]=f2bf(v.x); d[1]=f2bf(v.y); d[2]=f2bf(v.z); d[3]=f2bf(v.w);
        }
      } else {
        int ng = nbr[s];
        const float4* xi = (const float4*)(x + (size_t)node * NC);
        const float4* xj = (const float4*)(x + (size_t)ng * NC);
#pragma unroll
        for (int kk = 0; kk < 16; kk++) {
          float4 a = xi[kk], bq = xj[kk];
          int kc8 = 8 + (kk >> 1);
          int pos = ((kc8 ^ (r & 7)) << 3) + ((kk & 1) << 2);
          unsigned short* d = &etile[r*128 + pos];
          d[0]=f2bf(bq.x-a.x); d[1]=f2bf(bq.y-a.y); d[2]=f2bf(bq.z-a.z); d[3]=f2bf(bq.w-a.w);
        }
      }
    }
    __syncthreads();
    // hoist A fragments of e-tile (shared by both streams' GEMM1)
    short8 af[4][4];
#pragma unroll
    for (int ks = 0; ks < 4; ks++)
#pragma unroll
      for (int ri = 0; ri < 4; ri++) {
        int mm = ri*16 + n16;
        int kc8 = (ks*4 + q) ^ (mm & 7);
        af[ks][ri] = *(const short8*)&etile[mm*128 + kc8*8];
      }

#pragma unroll
    for (int st = 0; st < 2; st++) {
      const unsigned short* W1t = st ? tW1t : sW1t;
      const unsigned short* W2t = st ? tW2t : sW2t;
      const float* sc1 = st ? s1T : s1S;  const float* sh1 = st ? h1T : h1S;
      const float* sc2 = st ? s2T : s2S;  const float* sh2 = st ? h2T : h2S;
      float* ps  = st ? psT : psS;
      float* ps2 = st ? ps2T : ps2S;
      float* xout = st ? xoutT : xoutS;

      // GEMM1
      f32x4 acc[4][4];
#pragma unroll
      for (int ri = 0; ri < 4; ri++)
#pragma unroll
        for (int ci = 0; ci < 4; ci++)
          acc[ri][ci] = (f32x4){0.f,0.f,0.f,0.f};
#pragma unroll
      for (int ks = 0; ks < 4; ks++) {
        short8 bf[4];
#pragma unroll
        for (int ci = 0; ci < 4; ci++) {
          int col = cb + ci*16 + n16;
          bf[ci] = *(const short8*)(W1t + col*128 + ks*32 + q*8);
        }
#pragma unroll
        for (int ri = 0; ri < 4; ri++)
#pragma unroll
          for (int ci = 0; ci < 4; ci++)
            acc[ri][ci] = __builtin_amdgcn_mfma_f32_16x16x32_bf16(af[ks][ri], bf[ci], acc[ri][ci], 0, 0, 0);
      }
      if (MODE == 0) {
#pragma unroll
        for (int ci = 0; ci < 4; ci++)
#pragma unroll
          for (int ri = 0; ri < 4; ri++)
#pragma unroll
            for (int r = 0; r < 4; r++) {
              float v = acc[ri][ci][r];
              ps[ci] += v; ps2[ci] += v*v;
            }
        continue;
      }
      // bn1 + relu -> a-tile  (prior readers of atile finished: top sync (st=0) / sync below (st=1))
#pragma unroll
      for (int ri = 0; ri < 4; ri++)
#pragma unroll
        for (int ci = 0; ci < 4; ci++) {
          int colL = cb + ci*16 + n16;
          int kc8 = colL >> 3;
#pragma unroll
          for (int r = 0; r < 4; r++) {
            float v = fmaxf(acc[ri][ci][r] * sc1[ci] + sh1[ci], 0.f);
            int rowL = ri*16 + q*4 + r;
            int pos = ((kc8 ^ (rowL & 7)) << 3) + (colL & 7);
            atile[rowL*128 + pos] = f2bf(v);
          }
        }
      __syncthreads();
      // GEMM2
      f32x4 acc2[4][4];
#pragma unroll
      for (int ri = 0; ri < 4; ri++)
#pragma unroll
        for (int ci = 0; ci < 4; ci++)
          acc2[ri][ci] = (f32x4){0.f,0.f,0.f,0.f};
#pragma unroll
      for (int ks = 0; ks < 4; ks++) {
        short8 a2[4], bf[4];
#pragma unroll
        for (int ri = 0; ri < 4; ri++) {
          int mm = ri*16 + n16;
          int kc8 = (ks*4 + q) ^ (mm & 7);
          a2[ri] = *(const short8*)&atile[mm*128 + kc8*8];
        }
#pragma unroll
        for (int ci = 0; ci < 4; ci++) {
          int col = cb + ci*16 + n16;
          bf[ci] = *(const short8*)(W2t + col*128 + ks*32 + q*8);
        }
#pragma unroll
        for (int ri = 0; ri < 4; ri++)
#pragma unroll
          for (int ci = 0; ci < 4; ci++)
            acc2[ri][ci] = __builtin_amdgcn_mfma_f32_16x16x32_bf16(a2[ri], bf[ci], acc2[ri][ci], 0, 0, 0);
      }
      if (MODE == 1) {
#pragma unroll
        for (int ci = 0; ci < 4; ci++)
#pragma unroll
          for (int ri = 0; ri < 4; ri++)
#pragma unroll
            for (int r = 0; r < 4; r++) {
              float v = acc2[ri][ci][r];
              ps[ci] += v; ps2[ci] += v*v;
            }
      } else {
#pragma unroll
        for (int ri = 0; ri < 4; ri++)
#pragma unroll
          for (int ci = 0; ci < 4; ci++) {
            int col = cb + ci*16 + n16;
            float vm = 0.f;
#pragma unroll
            for (int r = 0; r < 4; r++) {
              float v = fmaxf(acc2[ri][ci][r] * sc2[ci] + sh2[ci], 0.f);
              vm = fmaxf(vm, v);
            }
            vm = fmaxf(vm, __shfl_xor(vm, 16, 64));
            vm = fmaxf(vm, __shfl_xor(vm, 32, 64));
            if (q == 0) {
              int node = (s0 >> 4) + ri;
              xout[(size_t)node*128 + col] = vm;
            }
          }
      }
      if (st == 0) __syncthreads();  // atile rewrite safety for stream t
    }
  }
  if (MODE <= 1) {
#pragma unroll
    for (int ci = 0; ci < 4; ci++) {
      int col = cb + ci*16 + n16;
      float a = psS[ci], a2 = ps2S[ci], b = psT[ci], b2 = ps2T[ci];
      a  += __shfl_xor(a, 16, 64);  a  += __shfl_xor(a, 32, 64);
      a2 += __shfl_xor(a2, 16, 64); a2 += __shfl_xor(a2, 32, 64);
      b  += __shfl_xor(b, 16, 64);  b  += __shfl_xor(b, 32, 64);
      b2 += __shfl_xor(b2, 16, 64); b2 += __shfl_xor(b2, 32, 64);
      if (q == 0) {
        atomicAdd(&statS[col], a);
        atomicAdd(&statS[128 + col], a2);
        atomicAdd(&statT[col], b);
        atomicAdd(&statT[128 + col], b2);
      }
    }
  }
}

// ---------------- finalize BN stats -> (scale, shift) ----------------
__global__ void finalize_kernel(const float* __restrict__ stats,
                                const float* __restrict__ g,
                                const float* __restrict__ be,
                                float* __restrict__ aff, float invcount) {
  int c = threadIdx.x;
  if (c < 128) {
    float mean = stats[c] * invcount;
    float var = stats[128 + c] * invcount - mean*mean;
    float scale = g[c] / sqrtf(var + EPSV);
    aff[c] = scale;
    aff[128 + c] = be[c] - mean * scale;
  }
}

// ---------------- final linear ----------------
__global__ __launch_bounds__(128) void final_pass(
    const float* __restrict__ xs,
    const float* __restrict__ xt,
    const unsigned short* __restrict__ fWt,
    float* __restrict__ gout,
    float* __restrict__ stats) {
  __shared__ unsigned short tile[64 * 256];
  int wave = threadIdx.x >> 6, lane = threadIdx.x & 63;
  int n16 = lane & 15, q = lane >> 4;
  int cb = wave * 64;
  int s0 = blockIdx.x * 64;
  {
    int r = threadIdx.x >> 1, half = threadIdx.x & 1;
    const float4* src = (const float4*)((half ? xt : xs) + (size_t)(s0 + r) * 128);
#pragma unroll
    for (int kk = 0; kk < 32; kk++) {
      float4 v = src[kk];
      int kc8 = half*16 + (kk >> 1);
      int pos = ((kc8 ^ (r & 7)) << 3) + ((kk & 1) << 2);
      unsigned short* d = &tile[r*256 + pos];
      d[0]=f2bf(v.x); d[1]=f2bf(v.y); d[2]=f2bf(v.z); d[3]=f2bf(v.w);
    }
  }
  __syncthreads();
  f32x4 acc[4][4];
#pragma unroll
  for (int ri = 0; ri < 4; ri++)
#pragma unroll
    for (int ci = 0; ci < 4; ci++)
      acc[ri][ci] = (f32x4){0.f,0.f,0.f,0.f};
#pragma unroll
  for (int ks = 0; ks < 8; ks++) {
    short8 af[4], bf[4];
#pragma unroll
    for (int ri = 0; ri < 4; ri++) {
      int mm = ri*16 + n16;
      int kc8 = (ks*4 + q) ^ (mm & 7);
      af[ri] = *(const short8*)&tile[mm*256 + kc8*8];
    }
#pragma unroll
    for (int ci = 0; ci < 4; ci++) {
      int col = cb + ci*16 + n16;
      bf[ci] = *(const short8*)(fWt + col*256 + ks*32 + q*8);
    }
#pragma unroll
    for (int ri = 0; ri < 4; ri++)
#pragma unroll
      for (int ci = 0; ci < 4; ci++)
        acc[ri][ci] = __builtin_amdgcn_mfma_f32_16x16x32_bf16(af[ri], bf[ci], acc[ri][ci], 0, 0, 0);
  }
  float ps[4] = {0,0,0,0}, ps2[4] = {0,0,0,0};
#pragma unroll
  for (int ri = 0; ri < 4; ri++)
#pragma unroll
    for (int ci = 0; ci < 4; ci++) {
      int col = cb + ci*16 + n16;
#pragma unroll
      for (int r = 0; r < 4; r++) {
        float v = acc[ri][ci][r];
        int row = s0 + ri*16 + q*4 + r;
        gout[(size_t)row*128 + col] = v;
        ps[ci] += v; ps2[ci] += v*v;
      }
    }
#pragma unroll
  for (int ci = 0; ci < 4; ci++) {
    float s = ps[ci], s2 = ps2[ci];
    s  += __shfl_xor(s, 16, 64);  s  += __shfl_xor(s, 32, 64);
    s2 += __shfl_xor(s2, 16, 64); s2 += __shfl_xor(s2, 32, 64);
    if (q == 0) {
      int col = cb + ci*16 + n16;
      atomicAdd(&stats[col], s);
      atomicAdd(&stats[128 + col], s2);
    }
  }
}

__global__ void apply_bn_kernel(float* __restrict__ out, const float* __restrict__ aff) {
  int i = blockIdx.x * blockDim.x + threadIdx.x;
  if (i < NS*NH) {
    int c = i & 127;
    out[i] = fmaxf(out[i] * aff[c] + aff[128 + c], 0.f);
  }
}

extern "C" void kernel_launch(void* const* d_in, const int* in_sizes, int n_in,
                              void* d_out, int out_size, void* d_ws, size_t ws_size,
                              hipStream_t stream) {
  const float* x   = (const float*)d_in[0];
  const float* sW1 = (const float*)d_in[2];
  const float* sg1 = (const float*)d_in[4];
  const float* sbe1= (const float*)d_in[5];
  const float* sW2 = (const float*)d_in[6];
  const float* sg2 = (const float*)d_in[8];
  const float* sbe2= (const float*)d_in[9];
  const float* tW1 = (const float*)d_in[10];
  const float* tg1 = (const float*)d_in[12];
  const float* tbe1= (const float*)d_in[13];
  const float* tW2 = (const float*)d_in[14];
  const float* tg2 = (const float*)d_in[16];
  const float* tbe2= (const float*)d_in[17];
  const float* fW  = (const float*)d_in[18];
  const float* fg  = (const float*)d_in[20];
  const float* fbe = (const float*)d_in[21];
  float* out = (float*)d_out;

  char* w = (char*)d_ws;
  float* sq = (float*)w;                 w += (size_t)NS*4;
  int* nbr = (int*)w;                    w += (size_t)NSK*4;
  unsigned short* sW1t = (unsigned short*)w; w += 32768;
  unsigned short* sW2t = (unsigned short*)w; w += 32768;
  unsigned short* tW1t = (unsigned short*)w; w += 32768;
  unsigned short* tW2t = (unsigned short*)w; w += 32768;
  unsigned short* fWt  = (unsigned short*)w; w += 65536;
  float* stats = (float*)w;              w += 2560*4;
  float* xs = (float*)w;                 w += (size_t)NS*NH*4;
  float* xt = (float*)w;                 w += (size_t)NS*NH*4;
  unsigned short* xh = (unsigned short*)w; w += (size_t)NS*64*2;
  unsigned short* xl = (unsigned short*)w; w += (size_t)NS*64*2;

  float* st_s1 = stats;        float* af_s1 = stats + 256;
  float* st_s2 = stats + 512;  float* af_s2 = stats + 768;
  float* st_t1 = stats + 1024; float* af_t1 = stats + 1280;
  float* st_t2 = stats + 1536; float* af_t2 = stats + 1792;
  float* st_f  = stats + 2048; float* af_f  = stats + 2304;

  hipMemsetAsync(stats, 0, 2560*4, stream);
  prep_weights<<<(4*16384 + 128*256 + 255)/256, 256, 0, stream>>>(
      sW1, sW2, tW1, tW2, fW, sW1t, sW2t, tW1t, tW2t, fWt);
  prep_x<<<NS/256, 256, 0, stream>>>(x, sq, xh, xl);
  knn3_kernel<<<NB*32, 256, 0, stream>>>(xh, xl, sq, nbr);

  const float inv1 = 1.f/(float)NSK, invf = 1.f/(float)NS;
  mlp_dual<0><<<1024,128,0,stream>>>(x, nbr, sW1t, sW2t, tW1t, tW2t,
      nullptr, nullptr, nullptr, nullptr, st_s1, st_t1, nullptr, nullptr);
  finalize_kernel<<<1,128,0,stream>>>(st_s1, sg1, sbe1, af_s1, inv1);
  finalize_kernel<<<1,128,0,stream>>>(st_t1, tg1, tbe1, af_t1, inv1);
  mlp_dual<1><<<1024,128,0,stream>>>(x, nbr, sW1t, sW2t, tW1t, tW2t,
      af_s1, nullptr, af_t1, nullptr, st_s2, st_t2, nullptr, nullptr);
  finalize_kernel<<<1,128,0,stream>>>(st_s2, sg2, sbe2, af_s2, inv1);
  finalize_kernel<<<1,128,0,stream>>>(st_t2, tg2, tbe2, af_t2, inv1);
  mlp_dual<2><<<1024,128,0,stream>>>(x, nbr, sW1t, sW2t, tW1t, tW2t,
      af_s1, af_s2, af_t1, af_t2, nullptr, nullptr, xs, xt);
  final_pass<<<NS/64, 128, 0, stream>>>(xs, xt, fWt, out, st_f);
  finalize_kernel<<<1,128,0,stream>>>(st_f, fg, fbe, af_f, invf);
  apply_bn_kernel<<<(NS*NH)/256, 256, 0, stream>>>(out, af_f);
}

// Round 4
// 1031.828 us; speedup vs baseline: 1.8189x; 1.0240x over previous
//
#include <hip/hip_runtime.h>
#include <hip/hip_bf16.h>
#include <stdint.h>

#define NB 16
#define NN 2048
#define NC 64
#define NH 128
#define NK 16
#define NS (NB*NN)
#define NSK (NS*NK)
#define EPSV 1e-5f

typedef __attribute__((ext_vector_type(8))) short short8;
typedef __attribute__((ext_vector_type(8))) _Float16 half8;
typedef __attribute__((ext_vector_type(8))) unsigned short ushort8;
typedef __attribute__((ext_vector_type(4))) float f32x4;

__device__ __forceinline__ unsigned short f2bf(float x) {
  union { float f; unsigned u; } v; v.f = x;
  unsigned r = v.u + 0x7fffu + ((v.u >> 16) & 1u);
  return (unsigned short)(r >> 16);
}

__device__ __forceinline__ unsigned orderf(float f) {
  unsigned u = __float_as_uint(f);
  return u ^ ((unsigned)((int)u >> 31) | 0x80000000u);
}

__device__ __forceinline__ unsigned long long shfl_xor_u64(unsigned long long v, int m) {
  unsigned lo = (unsigned)(v & 0xffffffffull);
  unsigned hi = (unsigned)(v >> 32);
  lo = __shfl_xor(lo, m, 64);
  hi = __shfl_xor(hi, m, 64);
  return (((unsigned long long)hi) << 32) | lo;
}

// ---------------- prep: squared norms + split-fp16 (hi, lo) ----------------
__global__ void prep_x(const float* __restrict__ x, float* __restrict__ sq,
                       unsigned short* __restrict__ xh, unsigned short* __restrict__ xl) {
  int i = blockIdx.x * blockDim.x + threadIdx.x;
  if (i >= NS) return;
  const float4* x4 = (const float4*)(x + (size_t)i * NC);
  float s = 0.f;
#pragma unroll
  for (int k = 0; k < 8; k++) {
    float4 a = x4[2*k], b = x4[2*k+1];
    float f[8] = {a.x,a.y,a.z,a.w,b.x,b.y,b.z,b.w};
    ushort8 hv, lv;
#pragma unroll
    for (int j = 0; j < 8; j++) {
      float v = f[j];
      s += v*v;
      _Float16 h = (_Float16)v;
      float r = v - (float)h;
      _Float16 l = (_Float16)r;
      union { _Float16 ff; unsigned short u; } ch, cl;
      ch.ff = h; cl.ff = l;
      hv[j] = ch.u; lv[j] = cl.u;
    }
    *(ushort8*)(xh + (size_t)i*64 + k*8) = hv;
    *(ushort8*)(xl + (size_t)i*64 + k*8) = lv;
  }
  sq[i] = s;
}

// ---------------- kNN v3: MFMA Gram + batched-filter sorted-insert top-16 ----------------
__global__ __launch_bounds__(256) void knn3_kernel(const unsigned short* __restrict__ xh,
                                                   const unsigned short* __restrict__ xl,
                                                   const float* __restrict__ sq,
                                                   int* __restrict__ nbr) {
  __shared__ unsigned short rAh[64*64], rAl[64*64];
  __shared__ unsigned short cBh[64*64], cBl[64*64];
  __shared__ float gram[64*68];
  __shared__ float sqc[64];
  int b = blockIdx.x >> 5;
  int rb = blockIdx.x & 31;
  int w = threadIdx.x >> 6, lane = threadIdx.x & 63;
  int n16 = lane & 15, q = lane >> 4;
  int rowbase = b*NN + rb*64;

  {
    int r = threadIdx.x >> 2;
    int c0 = (threadIdx.x & 3) * 2;
#pragma unroll
    for (int cc = 0; cc < 2; cc++) {
      int c = c0 + cc;
      int pos = (c ^ (r & 7)) * 8;
      *(ushort8*)&rAh[r*64 + pos] = *(const ushort8*)(xh + (size_t)(rowbase + r)*64 + c*8);
      *(ushort8*)&rAl[r*64 + pos] = *(const ushort8*)(xl + (size_t)(rowbase + r)*64 + c*8);
    }
  }
  __syncthreads();
  half8 ah[2], al[2];
  int m = w*16 + n16;
#pragma unroll
  for (int ks = 0; ks < 2; ks++) {
    int pos = ((ks*4 + q) ^ (m & 7)) * 8;
    ah[ks] = *(const half8*)&rAh[m*64 + pos];
    al[ks] = *(const half8*)&rAl[m*64 + pos];
  }
  float sqr = sq[rowbase + m];

  unsigned long long keys[16];   // sorted ascending; keys[15] = current worst
#pragma unroll
  for (int i = 0; i < 16; i++) keys[i] = ~0ull;
  unsigned whi = 0xffffffffu;

  for (int ch = 0; ch < 32; ch++) {
    int colbase = b*NN + ch*64;
    __syncthreads();
    {
      int r = threadIdx.x >> 2;
      int c0 = (threadIdx.x & 3) * 2;
#pragma unroll
      for (int cc = 0; cc < 2; cc++) {
        int c = c0 + cc;
        int pos = (c ^ (r & 7)) * 8;
        *(ushort8*)&cBh[r*64 + pos] = *(const ushort8*)(xh + (size_t)(colbase + r)*64 + c*8);
        *(ushort8*)&cBl[r*64 + pos] = *(const ushort8*)(xl + (size_t)(colbase + r)*64 + c*8);
      }
      if (threadIdx.x < 64) sqc[threadIdx.x] = sq[colbase + threadIdx.x];
    }
    __syncthreads();
    f32x4 acc[4];
#pragma unroll
    for (int ci = 0; ci < 4; ci++) acc[ci] = (f32x4){0.f,0.f,0.f,0.f};
#pragma unroll
    for (int ks = 0; ks < 2; ks++) {
#pragma unroll
      for (int ci = 0; ci < 4; ci++) {
        int n = ci*16 + n16;
        int pos = ((ks*4 + q) ^ (n & 7)) * 8;
        half8 bh = *(const half8*)&cBh[n*64 + pos];
        half8 bl = *(const half8*)&cBl[n*64 + pos];
        acc[ci] = __builtin_amdgcn_mfma_f32_16x16x32_f16(ah[ks], bh, acc[ci], 0, 0, 0);
        acc[ci] = __builtin_amdgcn_mfma_f32_16x16x32_f16(al[ks], bh, acc[ci], 0, 0, 0);
        acc[ci] = __builtin_amdgcn_mfma_f32_16x16x32_f16(ah[ks], bl, acc[ci], 0, 0, 0);
      }
    }
#pragma unroll
    for (int ci = 0; ci < 4; ci++)
#pragma unroll
      for (int r = 0; r < 4; r++)
        gram[(w*16 + q*4 + r)*68 + ci*16 + n16] = acc[ci][r];
    __syncthreads();
    const float* gp = &gram[(size_t)(w*16 + n16)*68 + q*16];
    const float* sc = &sqc[q*16];
    unsigned mask = 0;
#pragma unroll
    for (int i4 = 0; i4 < 4; i4++) {
      float4 g4 = *(const float4*)(gp + i4*4);
      float4 s4 = *(const float4*)(sc + i4*4);
      float d0 = fmaf(-2.f, g4.x, sqr + s4.x);
      float d1 = fmaf(-2.f, g4.y, sqr + s4.y);
      float d2 = fmaf(-2.f, g4.z, sqr + s4.z);
      float d3 = fmaf(-2.f, g4.w, sqr + s4.w);
      if (orderf(d0) <= whi) mask |= 1u << (i4*4+0);
      if (orderf(d1) <= whi) mask |= 1u << (i4*4+1);
      if (orderf(d2) <= whi) mask |= 1u << (i4*4+2);
      if (orderf(d3) <= whi) mask |= 1u << (i4*4+3);
    }
    while (mask) {
      int i = __builtin_ctz(mask);
      mask &= mask - 1;
      float g = gp[i];
      float dd = fmaf(-2.f, g, sqr + sc[i]);
      unsigned long long key = ((unsigned long long)orderf(dd) << 32) |
                               (unsigned)(colbase + q*16 + i);
#pragma unroll
      for (int j = 0; j < 16; j++) {
        bool cl = key < keys[j];
        unsigned long long lo = cl ? key : keys[j];
        key = cl ? keys[j] : key;
        keys[j] = lo;
      }
      whi = (unsigned)(keys[15] >> 32);
    }
  }
  for (int j = 0; j < NK; j++) {
    unsigned long long mk = keys[0];
#pragma unroll
    for (int i = 1; i < 16; i++) mk = (keys[i] < mk) ? keys[i] : mk;
    unsigned long long o = shfl_xor_u64(mk, 16); mk = (o < mk) ? o : mk;
    o = shfl_xor_u64(mk, 32); mk = (o < mk) ? o : mk;
#pragma unroll
    for (int i = 0; i < 16; i++) if (keys[i] == mk) keys[i] = ~0ull;
    if (q == 0) nbr[(size_t)(rowbase + m)*NK + j] = (int)(mk & 0xffffffffu);
  }
}

// ---------------- weight prep ----------------
__global__ void prep_weights(const float* __restrict__ sW1, const float* __restrict__ sW2,
                             const float* __restrict__ tW1, const float* __restrict__ tW2,
                             const float* __restrict__ fW,
                             unsigned short* __restrict__ sW1t, unsigned short* __restrict__ sW2t,
                             unsigned short* __restrict__ tW1t, unsigned short* __restrict__ tW2t,
                             unsigned short* __restrict__ fWt) {
  int i = blockIdx.x * blockDim.x + threadIdx.x;
  if (i < 4*16384) {
    int mi = i >> 14, e = i & 16383;
    int h = e >> 7, k = e & 127;
    const float* src = (mi==0) ? sW1 : (mi==1) ? sW2 : (mi==2) ? tW1 : tW2;
    unsigned short* dst = (mi==0) ? sW1t : (mi==1) ? sW2t : (mi==2) ? tW1t : tW2t;
    dst[h*128 + k] = f2bf(src[k*128 + h]);
  } else {
    int e = i - 4*16384;
    if (e < 128*256) {
      int h = e >> 8, k = e & 255;
      fWt[h*256 + k] = f2bf(fW[k*128 + h]);
    }
  }
}

// ---------------- dual-stream fused EdgeConv MLP pass (4-wave, 32-col bands) ----------------
// MODE 0: GEMM1 -> stats(h1) both streams
// MODE 1: GEMM1 -> bn1+relu -> GEMM2 -> stats(h2) both streams
// MODE 2: ... -> bn2+relu -> max over K -> xout both streams
// 256 threads: wave w owns cols w*32..w*32+31. acc = 4x2 frags (32 VGPRs).
template<int MODE>
__global__ __launch_bounds__(256, 4) void mlp_dual(
    const float* __restrict__ x,
    const int* __restrict__ nbr,
    const unsigned short* __restrict__ sW1t, const unsigned short* __restrict__ sW2t,
    const unsigned short* __restrict__ tW1t, const unsigned short* __restrict__ tW2t,
    const float* __restrict__ affS1, const float* __restrict__ affS2,
    const float* __restrict__ affT1, const float* __restrict__ affT2,
    float* __restrict__ statS, float* __restrict__ statT,
    float* __restrict__ xoutS, float* __restrict__ xoutT) {
  __shared__ unsigned short etile[64 * 128];
  __shared__ unsigned short atile[(MODE >= 1) ? 64 * 128 : 64];
  int wave = threadIdx.x >> 6;
  int lane = threadIdx.x & 63;
  int n16 = lane & 15;
  int q = lane >> 4;
  int cb = wave * 32;

  float s1S[2], h1S[2], s2S[2], h2S[2];
  float s1T[2], h1T[2], s2T[2], h2T[2];
  if (MODE >= 1) {
#pragma unroll
    for (int ci = 0; ci < 2; ci++) {
      int col = cb + ci*16 + n16;
      s1S[ci] = affS1[col]; h1S[ci] = affS1[128 + col];
      s1T[ci] = affT1[col]; h1T[ci] = affT1[128 + col];
    }
  }
  if (MODE == 2) {
#pragma unroll
    for (int ci = 0; ci < 2; ci++) {
      int col = cb + ci*16 + n16;
      s2S[ci] = affS2[col]; h2S[ci] = affS2[128 + col];
      s2T[ci] = affT2[col]; h2T[ci] = affT2[128 + col];
    }
  }
  float psS[2] = {0,0}, ps2S[2] = {0,0};
  float psT[2] = {0,0}, ps2T[2] = {0,0};

  for (int it = 0; it < 8; it++) {
    int tileIdx = blockIdx.x * 8 + it;
    int s0 = tileIdx * 64;
    __syncthreads();
    // stage e-tile once: 4 threads per row (64 rows)
    {
      int r = threadIdx.x >> 2, part = threadIdx.x & 3;
      int s = s0 + r;
      int node = s >> 4;
      if (part < 2) {
        // xi, channel halves 0/1
        const float4* xp = (const float4*)(x + (size_t)node * NC) + part*8;
#pragma unroll
        for (int kk8 = 0; kk8 < 8; kk8++) {
          int kk = part*8 + kk8;
          float4 v = xp[kk8];
          int kc8 = kk >> 1;
          int pos = ((kc8 ^ (r & 7)) << 3) + ((kk & 1) << 2);
          unsigned short* d = &etile[r*128 + pos];
          d[0]=f2bf(v.x); d[1]=f2bf(v.y); d[2]=f2bf(v.z); d[3]=f2bf(v.w);
        }
      } else {
        int half = part - 2;
        int ng = nbr[s];
        const float4* xi = (const float4*)(x + (size_t)node * NC) + half*8;
        const float4* xj = (const float4*)(x + (size_t)ng * NC) + half*8;
#pragma unroll
        for (int kk8 = 0; kk8 < 8; kk8++) {
          int kk = half*8 + kk8;
          float4 a = xi[kk8], bq = xj[kk8];
          int kc8 = 8 + (kk >> 1);
          int pos = ((kc8 ^ (r & 7)) << 3) + ((kk & 1) << 2);
          unsigned short* d = &etile[r*128 + pos];
          d[0]=f2bf(bq.x-a.x); d[1]=f2bf(bq.y-a.y); d[2]=f2bf(bq.z-a.z); d[3]=f2bf(bq.w-a.w);
        }
      }
    }
    __syncthreads();

#pragma unroll
    for (int st = 0; st < 2; st++) {
      const unsigned short* W1t = st ? tW1t : sW1t;
      const unsigned short* W2t = st ? tW2t : sW2t;
      const float* sc1 = st ? s1T : s1S;  const float* sh1 = st ? h1T : h1S;
      const float* sc2 = st ? s2T : s2S;  const float* sh2 = st ? h2T : h2S;
      float* ps  = st ? psT : psS;
      float* ps2 = st ? ps2T : ps2S;
      float* xout = st ? xoutT : xoutS;

      // GEMM1: 64 rows x 32 cols per wave
      f32x4 acc[4][2];
#pragma unroll
      for (int ri = 0; ri < 4; ri++)
#pragma unroll
        for (int ci = 0; ci < 2; ci++)
          acc[ri][ci] = (f32x4){0.f,0.f,0.f,0.f};
#pragma unroll
      for (int ks = 0; ks < 4; ks++) {
        short8 af[4], bf[2];
#pragma unroll
        for (int ri = 0; ri < 4; ri++) {
          int mm = ri*16 + n16;
          int kc8 = (ks*4 + q) ^ (mm & 7);
          af[ri] = *(const short8*)&etile[mm*128 + kc8*8];
        }
#pragma unroll
        for (int ci = 0; ci < 2; ci++) {
          int col = cb + ci*16 + n16;
          bf[ci] = *(const short8*)(W1t + col*128 + ks*32 + q*8);
        }
#pragma unroll
        for (int ri = 0; ri < 4; ri++)
#pragma unroll
          for (int ci = 0; ci < 2; ci++)
            acc[ri][ci] = __builtin_amdgcn_mfma_f32_16x16x32_bf16(af[ri], bf[ci], acc[ri][ci], 0, 0, 0);
      }
      if (MODE == 0) {
#pragma unroll
        for (int ci = 0; ci < 2; ci++)
#pragma unroll
          for (int ri = 0; ri < 4; ri++)
#pragma unroll
            for (int r = 0; r < 4; r++) {
              float v = acc[ri][ci][r];
              ps[ci] += v; ps2[ci] += v*v;
            }
        continue;
      }
      // bn1 + relu -> a-tile
#pragma unroll
      for (int ri = 0; ri < 4; ri++)
#pragma unroll
        for (int ci = 0; ci < 2; ci++) {
          int colL = cb + ci*16 + n16;
          int kc8 = colL >> 3;
#pragma unroll
          for (int r = 0; r < 4; r++) {
            float v = fmaxf(acc[ri][ci][r] * sc1[ci] + sh1[ci], 0.f);
            int rowL = ri*16 + q*4 + r;
            int pos = ((kc8 ^ (rowL & 7)) << 3) + (colL & 7);
            atile[rowL*128 + pos] = f2bf(v);
          }
        }
      __syncthreads();
      // GEMM2
      f32x4 acc2[4][2];
#pragma unroll
      for (int ri = 0; ri < 4; ri++)
#pragma unroll
        for (int ci = 0; ci < 2; ci++)
          acc2[ri][ci] = (f32x4){0.f,0.f,0.f,0.f};
#pragma unroll
      for (int ks = 0; ks < 4; ks++) {
        short8 a2[4], bf[2];
#pragma unroll
        for (int ri = 0; ri < 4; ri++) {
          int mm = ri*16 + n16;
          int kc8 = (ks*4 + q) ^ (mm & 7);
          a2[ri] = *(const short8*)&atile[mm*128 + kc8*8];
        }
#pragma unroll
        for (int ci = 0; ci < 2; ci++) {
          int col = cb + ci*16 + n16;
          bf[ci] = *(const short8*)(W2t + col*128 + ks*32 + q*8);
        }
#pragma unroll
        for (int ri = 0; ri < 4; ri++)
#pragma unroll
          for (int ci = 0; ci < 2; ci++)
            acc2[ri][ci] = __builtin_amdgcn_mfma_f32_16x16x32_bf16(a2[ri], bf[ci], acc2[ri][ci], 0, 0, 0);
      }
      if (MODE == 1) {
#pragma unroll
        for (int ci = 0; ci < 2; ci++)
#pragma unroll
          for (int ri = 0; ri < 4; ri++)
#pragma unroll
            for (int r = 0; r < 4; r++) {
              float v = acc2[ri][ci][r];
              ps[ci] += v; ps2[ci] += v*v;
            }
      } else {
#pragma unroll
        for (int ri = 0; ri < 4; ri++)
#pragma unroll
          for (int ci = 0; ci < 2; ci++) {
            int col = cb + ci*16 + n16;
            float vm = 0.f;
#pragma unroll
            for (int r = 0; r < 4; r++) {
              float v = fmaxf(acc2[ri][ci][r] * sc2[ci] + sh2[ci], 0.f);
              vm = fmaxf(vm, v);
            }
            vm = fmaxf(vm, __shfl_xor(vm, 16, 64));
            vm = fmaxf(vm, __shfl_xor(vm, 32, 64));
            if (q == 0) {
              int node = (s0 >> 4) + ri;
              xout[(size_t)node*128 + col] = vm;
            }
          }
      }
      if (st == 0) __syncthreads();  // atile rewrite safety for stream t
    }
  }
  if (MODE <= 1) {
#pragma unroll
    for (int ci = 0; ci < 2; ci++) {
      int col = cb + ci*16 + n16;
      float a = psS[ci], a2 = ps2S[ci], b = psT[ci], b2 = ps2T[ci];
      a  += __shfl_xor(a, 16, 64);  a  += __shfl_xor(a, 32, 64);
      a2 += __shfl_xor(a2, 16, 64); a2 += __shfl_xor(a2, 32, 64);
      b  += __shfl_xor(b, 16, 64);  b  += __shfl_xor(b, 32, 64);
      b2 += __shfl_xor(b2, 16, 64); b2 += __shfl_xor(b2, 32, 64);
      if (q == 0) {
        atomicAdd(&statS[col], a);
        atomicAdd(&statS[128 + col], a2);
        atomicAdd(&statT[col], b);
        atomicAdd(&statT[128 + col], b2);
      }
    }
  }
}

// ---------------- finalize BN stats -> (scale, shift) ----------------
__global__ void finalize_kernel(const float* __restrict__ stats,
                                const float* __restrict__ g,
                                const float* __restrict__ be,
                                float* __restrict__ aff, float invcount) {
  int c = threadIdx.x;
  if (c < 128) {
    float mean = stats[c] * invcount;
    float var = stats[128 + c] * invcount - mean*mean;
    float scale = g[c] / sqrtf(var + EPSV);
    aff[c] = scale;
    aff[128 + c] = be[c] - mean * scale;
  }
}

// ---------------- final linear ----------------
__global__ __launch_bounds__(128) void final_pass(
    const float* __restrict__ xs,
    const float* __restrict__ xt,
    const unsigned short* __restrict__ fWt,
    float* __restrict__ gout,
    float* __restrict__ stats) {
  __shared__ unsigned short tile[64 * 256];
  int wave = threadIdx.x >> 6, lane = threadIdx.x & 63;
  int n16 = lane & 15, q = lane >> 4;
  int cb = wave * 64;
  int s0 = blockIdx.x * 64;
  {
    int r = threadIdx.x >> 1, half = threadIdx.x & 1;
    const float4* src = (const float4*)((half ? xt : xs) + (size_t)(s0 + r) * 128);
#pragma unroll
    for (int kk = 0; kk < 32; kk++) {
      float4 v = src[kk];
      int kc8 = half*16 + (kk >> 1);
      int pos = ((kc8 ^ (r & 7)) << 3) + ((kk & 1) << 2);
      unsigned short* d = &tile[r*256 + pos];
      d[0]=f2bf(v.x); d[1]=f2bf(v.y); d[2]=f2bf(v.z); d[3]=f2bf(v.w);
    }
  }
  __syncthreads();
  f32x4 acc[4][4];
#pragma unroll
  for (int ri = 0; ri < 4; ri++)
#pragma unroll
    for (int ci = 0; ci < 4; ci++)
      acc[ri][ci] = (f32x4){0.f,0.f,0.f,0.f};
#pragma unroll
  for (int ks = 0; ks < 8; ks++) {
    short8 af[4], bf[4];
#pragma unroll
    for (int ri = 0; ri < 4; ri++) {
      int mm = ri*16 + n16;
      int kc8 = (ks*4 + q) ^ (mm & 7);
      af[ri] = *(const short8*)&tile[mm*256 + kc8*8];
    }
#pragma unroll
    for (int ci = 0; ci < 4; ci++) {
      int col = cb + ci*16 + n16;
      bf[ci] = *(const short8*)(fWt + col*256 + ks*32 + q*8);
    }
#pragma unroll
    for (int ri = 0; ri < 4; ri++)
#pragma unroll
      for (int ci = 0; ci < 4; ci++)
        acc[ri][ci] = __builtin_amdgcn_mfma_f32_16x16x32_bf16(af[ri], bf[ci], acc[ri][ci], 0, 0, 0);
  }
  float ps[4] = {0,0,0,0}, ps2[4] = {0,0,0,0};
#pragma unroll
  for (int ri = 0; ri < 4; ri++)
#pragma unroll
    for (int ci = 0; ci < 4; ci++) {
      int col = cb + ci*16 + n16;
#pragma unroll
      for (int r = 0; r < 4; r++) {
        float v = acc[ri][ci][r];
        int row = s0 + ri*16 + q*4 + r;
        gout[(size_t)row*128 + col] = v;
        ps[ci] += v; ps2[ci] += v*v;
      }
    }
#pragma unroll
  for (int ci = 0; ci < 4; ci++) {
    float s = ps[ci], s2 = ps2[ci];
    s  += __shfl_xor(s, 16, 64);  s  += __shfl_xor(s, 32, 64);
    s2 += __shfl_xor(s2, 16, 64); s2 += __shfl_xor(s2, 32, 64);
    if (q == 0) {
      int col = cb + ci*16 + n16;
      atomicAdd(&stats[col], s);
      atomicAdd(&stats[128 + col], s2);
    }
  }
}

__global__ void apply_bn_kernel(float* __restrict__ out, const float* __restrict__ aff) {
  int i = blockIdx.x * blockDim.x + threadIdx.x;
  if (i < NS*NH) {
    int c = i & 127;
    out[i] = fmaxf(out[i] * aff[c] + aff[128 + c], 0.f);
  }
}

extern "C" void kernel_launch(void* const* d_in, const int* in_sizes, int n_in,
                              void* d_out, int out_size, void* d_ws, size_t ws_size,
                              hipStream_t stream) {
  const float* x   = (const float*)d_in[0];
  const float* sW1 = (const float*)d_in[2];
  const float* sg1 = (const float*)d_in[4];
  const float* sbe1= (const float*)d_in[5];
  const float* sW2 = (const float*)d_in[6];
  const float* sg2 = (const float*)d_in[8];
  const float* sbe2= (const float*)d_in[9];
  const float* tW1 = (const float*)d_in[10];
  const float* tg1 = (const float*)d_in[12];
  const float* tbe1= (const float*)d_in[13];
  const float* tW2 = (const float*)d_in[14];
  const float* tg2 = (const float*)d_in[16];
  const float* tbe2= (const float*)d_in[17];
  const float* fW  = (const float*)d_in[18];
  const float* fg  = (const float*)d_in[20];
  const float* fbe = (const float*)d_in[21];
  float* out = (float*)d_out;

  char* w = (char*)d_ws;
  float* sq = (float*)w;                 w += (size_t)NS*4;
  int* nbr = (int*)w;                    w += (size_t)NSK*4;
  unsigned short* sW1t = (unsigned short*)w; w += 32768;
  unsigned short* sW2t = (unsigned short*)w; w += 32768;
  unsigned short* tW1t = (unsigned short*)w; w += 32768;
  unsigned short* tW2t = (unsigned short*)w; w += 32768;
  unsigned short* fWt  = (unsigned short*)w; w += 65536;
  float* stats = (float*)w;              w += 2560*4;
  float* xs = (float*)w;                 w += (size_t)NS*NH*4;
  float* xt = (float*)w;                 w += (size_t)NS*NH*4;
  unsigned short* xh = (unsigned short*)w; w += (size_t)NS*64*2;
  unsigned short* xl = (unsigned short*)w; w += (size_t)NS*64*2;

  float* st_s1 = stats;        float* af_s1 = stats + 256;
  float* st_s2 = stats + 512;  float* af_s2 = stats + 768;
  float* st_t1 = stats + 1024; float* af_t1 = stats + 1280;
  float* st_t2 = stats + 1536; float* af_t2 = stats + 1792;
  float* st_f  = stats + 2048; float* af_f  = stats + 2304;

  hipMemsetAsync(stats, 0, 2560*4, stream);
  prep_weights<<<(4*16384 + 128*256 + 255)/256, 256, 0, stream>>>(
      sW1, sW2, tW1, tW2, fW, sW1t, sW2t, tW1t, tW2t, fWt);
  prep_x<<<NS/256, 256, 0, stream>>>(x, sq, xh, xl);
  knn3_kernel<<<NB*32, 256, 0, stream>>>(xh, xl, sq, nbr);

  const float inv1 = 1.f/(float)NSK, invf = 1.f/(float)NS;
  mlp_dual<0><<<1024,256,0,stream>>>(x, nbr, sW1t, sW2t, tW1t, tW2t,
      nullptr, nullptr, nullptr, nullptr, st_s1, st_t1, nullptr, nullptr);
  finalize_kernel<<<1,128,0,stream>>>(st_s1, sg1, sbe1, af_s1, inv1);
  finalize_kernel<<<1,128,0,stream>>>(st_t1, tg1, tbe1, af_t1, inv1);
  mlp_dual<1><<<1024,256,0,stream>>>(x, nbr, sW1t, sW2t, tW1t, tW2t,
      af_s1, nullptr, af_t1, nullptr, st_s2, st_t2, nullptr, nullptr);
  finalize_kernel<<<1,128,0,stream>>>(st_s2, sg2, sbe2, af_s2, inv1);
  finalize_kernel<<<1,128,0,stream>>>(st_t2, tg2, tbe2, af_t2, inv1);
  mlp_dual<2><<<1024,256,0,stream>>>(x, nbr, sW1t, sW2t, tW1t, tW2t,
      af_s1, af_s2, af_t1, af_t2, nullptr, nullptr, xs, xt);
  final_pass<<<NS/64, 128, 0, stream>>>(xs, xt, fWt, out, st_f);
  finalize_kernel<<<1,128,0,stream>>>(st_f, fg, fbe, af_f, invf);
  apply_bn_kernel<<<(NS*NH)/256, 256, 0, stream>>>(out, af_f);
}

// Round 5
// 588.874 us; speedup vs baseline: 3.1871x; 1.7522x over previous
//
#include <hip/hip_runtime.h>
#include <hip/hip_bf16.h>
#include <stdint.h>

#define NB 16
#define NN 2048
#define NC 64
#define NH 128
#define NK 16
#define NS (NB*NN)
#define NSK (NS*NK)
#define EPSV 1e-5f

typedef __attribute__((ext_vector_type(8))) short short8;
typedef __attribute__((ext_vector_type(8))) _Float16 half8;
typedef __attribute__((ext_vector_type(8))) unsigned short ushort8;
typedef __attribute__((ext_vector_type(4))) float f32x4;

__device__ __forceinline__ unsigned short f2bf(float x) {
  union { float f; unsigned u; } v; v.f = x;
  unsigned r = v.u + 0x7fffu + ((v.u >> 16) & 1u);
  return (unsigned short)(r >> 16);
}

__device__ __forceinline__ unsigned orderf(float f) {
  unsigned u = __float_as_uint(f);
  return u ^ ((unsigned)((int)u >> 31) | 0x80000000u);
}

__device__ __forceinline__ unsigned long long shfl_xor_u64(unsigned long long v, int m) {
  unsigned lo = (unsigned)(v & 0xffffffffull);
  unsigned hi = (unsigned)(v >> 32);
  lo = __shfl_xor(lo, m, 64);
  hi = __shfl_xor(hi, m, 64);
  return (((unsigned long long)hi) << 32) | lo;
}

// ---------------- prep: squared norms + split-fp16 (hi, lo) ----------------
__global__ void prep_x(const float* __restrict__ x, float* __restrict__ sq,
                       unsigned short* __restrict__ xh, unsigned short* __restrict__ xl) {
  int i = blockIdx.x * blockDim.x + threadIdx.x;
  if (i >= NS) return;
  const float4* x4 = (const float4*)(x + (size_t)i * NC);
  float s = 0.f;
#pragma unroll
  for (int k = 0; k < 8; k++) {
    float4 a = x4[2*k], b = x4[2*k+1];
    float f[8] = {a.x,a.y,a.z,a.w,b.x,b.y,b.z,b.w};
    ushort8 hv, lv;
#pragma unroll
    for (int j = 0; j < 8; j++) {
      float v = f[j];
      s += v*v;
      _Float16 h = (_Float16)v;
      float r = v - (float)h;
      _Float16 l = (_Float16)r;
      union { _Float16 ff; unsigned short u; } ch, cl;
      ch.ff = h; cl.ff = l;
      hv[j] = ch.u; lv[j] = cl.u;
    }
    *(ushort8*)(xh + (size_t)i*64 + k*8) = hv;
    *(ushort8*)(xl + (size_t)i*64 + k*8) = lv;
  }
  sq[i] = s;
}

// ---------------- kNN v3 (unchanged from round 3/4) ----------------
__global__ __launch_bounds__(256) void knn3_kernel(const unsigned short* __restrict__ xh,
                                                   const unsigned short* __restrict__ xl,
                                                   const float* __restrict__ sq,
                                                   int* __restrict__ nbr) {
  __shared__ unsigned short rAh[64*64], rAl[64*64];
  __shared__ unsigned short cBh[64*64], cBl[64*64];
  __shared__ float gram[64*68];
  __shared__ float sqc[64];
  int b = blockIdx.x >> 5;
  int rb = blockIdx.x & 31;
  int w = threadIdx.x >> 6, lane = threadIdx.x & 63;
  int n16 = lane & 15, q = lane >> 4;
  int rowbase = b*NN + rb*64;

  {
    int r = threadIdx.x >> 2;
    int c0 = (threadIdx.x & 3) * 2;
#pragma unroll
    for (int cc = 0; cc < 2; cc++) {
      int c = c0 + cc;
      int pos = (c ^ (r & 7)) * 8;
      *(ushort8*)&rAh[r*64 + pos] = *(const ushort8*)(xh + (size_t)(rowbase + r)*64 + c*8);
      *(ushort8*)&rAl[r*64 + pos] = *(const ushort8*)(xl + (size_t)(rowbase + r)*64 + c*8);
    }
  }
  __syncthreads();
  half8 ah[2], al[2];
  int m = w*16 + n16;
#pragma unroll
  for (int ks = 0; ks < 2; ks++) {
    int pos = ((ks*4 + q) ^ (m & 7)) * 8;
    ah[ks] = *(const half8*)&rAh[m*64 + pos];
    al[ks] = *(const half8*)&rAl[m*64 + pos];
  }
  float sqr = sq[rowbase + m];

  unsigned long long keys[16];
#pragma unroll
  for (int i = 0; i < 16; i++) keys[i] = ~0ull;
  unsigned whi = 0xffffffffu;

  for (int ch = 0; ch < 32; ch++) {
    int colbase = b*NN + ch*64;
    __syncthreads();
    {
      int r = threadIdx.x >> 2;
      int c0 = (threadIdx.x & 3) * 2;
#pragma unroll
      for (int cc = 0; cc < 2; cc++) {
        int c = c0 + cc;
        int pos = (c ^ (r & 7)) * 8;
        *(ushort8*)&cBh[r*64 + pos] = *(const ushort8*)(xh + (size_t)(colbase + r)*64 + c*8);
        *(ushort8*)&cBl[r*64 + pos] = *(const ushort8*)(xl + (size_t)(colbase + r)*64 + c*8);
      }
      if (threadIdx.x < 64) sqc[threadIdx.x] = sq[colbase + threadIdx.x];
    }
    __syncthreads();
    f32x4 acc[4];
#pragma unroll
    for (int ci = 0; ci < 4; ci++) acc[ci] = (f32x4){0.f,0.f,0.f,0.f};
#pragma unroll
    for (int ks = 0; ks < 2; ks++) {
#pragma unroll
      for (int ci = 0; ci < 4; ci++) {
        int n = ci*16 + n16;
        int pos = ((ks*4 + q) ^ (n & 7)) * 8;
        half8 bh = *(const half8*)&cBh[n*64 + pos];
        half8 bl = *(const half8*)&cBl[n*64 + pos];
        acc[ci] = __builtin_amdgcn_mfma_f32_16x16x32_f16(ah[ks], bh, acc[ci], 0, 0, 0);
        acc[ci] = __builtin_amdgcn_mfma_f32_16x16x32_f16(al[ks], bh, acc[ci], 0, 0, 0);
        acc[ci] = __builtin_amdgcn_mfma_f32_16x16x32_f16(ah[ks], bl, acc[ci], 0, 0, 0);
      }
    }
#pragma unroll
    for (int ci = 0; ci < 4; ci++)
#pragma unroll
      for (int r = 0; r < 4; r++)
        gram[(w*16 + q*4 + r)*68 + ci*16 + n16] = acc[ci][r];
    __syncthreads();
    const float* gp = &gram[(size_t)(w*16 + n16)*68 + q*16];
    const float* sc = &sqc[q*16];
    unsigned mask = 0;
#pragma unroll
    for (int i4 = 0; i4 < 4; i4++) {
      float4 g4 = *(const float4*)(gp + i4*4);
      float4 s4 = *(const float4*)(sc + i4*4);
      float d0 = fmaf(-2.f, g4.x, sqr + s4.x);
      float d1 = fmaf(-2.f, g4.y, sqr + s4.y);
      float d2 = fmaf(-2.f, g4.z, sqr + s4.z);
      float d3 = fmaf(-2.f, g4.w, sqr + s4.w);
      if (orderf(d0) <= whi) mask |= 1u << (i4*4+0);
      if (orderf(d1) <= whi) mask |= 1u << (i4*4+1);
      if (orderf(d2) <= whi) mask |= 1u << (i4*4+2);
      if (orderf(d3) <= whi) mask |= 1u << (i4*4+3);
    }
    while (mask) {
      int i = __builtin_ctz(mask);
      mask &= mask - 1;
      float g = gp[i];
      float dd = fmaf(-2.f, g, sqr + sc[i]);
      unsigned long long key = ((unsigned long long)orderf(dd) << 32) |
                               (unsigned)(colbase + q*16 + i);
#pragma unroll
      for (int j = 0; j < 16; j++) {
        bool cl = key < keys[j];
        unsigned long long lo = cl ? key : keys[j];
        key = cl ? keys[j] : key;
        keys[j] = lo;
      }
      whi = (unsigned)(keys[15] >> 32);
    }
  }
  for (int j = 0; j < NK; j++) {
    unsigned long long mk = keys[0];
#pragma unroll
    for (int i = 1; i < 16; i++) mk = (keys[i] < mk) ? keys[i] : mk;
    unsigned long long o = shfl_xor_u64(mk, 16); mk = (o < mk) ? o : mk;
    o = shfl_xor_u64(mk, 32); mk = (o < mk) ? o : mk;
#pragma unroll
    for (int i = 0; i < 16; i++) if (keys[i] == mk) keys[i] = ~0ull;
    if (q == 0) nbr[(size_t)(rowbase + m)*NK + j] = (int)(mk & 0xffffffffu);
  }
}

// ---------------- weight prep: transpose + bf16, Wt[col][k] ----------------
__global__ void prep_weights(const float* __restrict__ sW1, const float* __restrict__ sW2,
                             const float* __restrict__ tW1, const float* __restrict__ tW2,
                             const float* __restrict__ fW,
                             unsigned short* __restrict__ sW1t, unsigned short* __restrict__ sW2t,
                             unsigned short* __restrict__ tW1t, unsigned short* __restrict__ tW2t,
                             unsigned short* __restrict__ fWt) {
  int i = blockIdx.x * blockDim.x + threadIdx.x;
  if (i < 4*16384) {
    int mi = i >> 14, e = i & 16383;
    int h = e >> 7, k = e & 127;
    const float* src = (mi==0) ? sW1 : (mi==1) ? sW2 : (mi==2) ? tW1 : tW2;
    unsigned short* dst = (mi==0) ? sW1t : (mi==1) ? sW2t : (mi==2) ? tW1t : tW2t;
    dst[h*128 + k] = f2bf(src[k*128 + h]);
  } else {
    int e = i - 4*16384;
    if (e < 128*256) {
      int h = e >> 8, k = e & 255;
      fWt[h*256 + k] = f2bf(fW[k*128 + h]);
    }
  }
}

// ---------------- per-node term: P = bf16(x) @ W1_top (both streams) ----------------
__global__ __launch_bounds__(256) void pnode_kernel(
    const float* __restrict__ x,
    const unsigned short* __restrict__ sW1t, const unsigned short* __restrict__ tW1t,
    float* __restrict__ PS, float* __restrict__ PT) {
  __shared__ unsigned short xt_[64*64];
  int rowbase = blockIdx.x * 64;
  int lane = threadIdx.x & 63;
  int wave = threadIdx.x >> 6;
  int n16 = lane & 15, q = lane >> 4;
  int cb = wave * 32;
  {
    int r = threadIdx.x >> 2, part = threadIdx.x & 3;
    const float4* xp = (const float4*)(x + (size_t)(rowbase + r) * NC) + part*4;
#pragma unroll
    for (int cc = 0; cc < 2; cc++) {
      int c = part*2 + cc;
      float4 a = xp[cc*2], b = xp[cc*2+1];
      int pos = (c ^ (r & 7)) * 8;
      unsigned short* d = &xt_[r*64 + pos];
      d[0]=f2bf(a.x); d[1]=f2bf(a.y); d[2]=f2bf(a.z); d[3]=f2bf(a.w);
      d[4]=f2bf(b.x); d[5]=f2bf(b.y); d[6]=f2bf(b.z); d[7]=f2bf(b.w);
    }
  }
  __syncthreads();
  f32x4 aS[4][2], aT[4][2];
#pragma unroll
  for (int ri = 0; ri < 4; ri++)
#pragma unroll
    for (int ci = 0; ci < 2; ci++) {
      aS[ri][ci] = (f32x4){0.f,0.f,0.f,0.f};
      aT[ri][ci] = (f32x4){0.f,0.f,0.f,0.f};
    }
#pragma unroll
  for (int ks = 0; ks < 2; ks++) {
    short8 af[4];
#pragma unroll
    for (int ri = 0; ri < 4; ri++) {
      int m = ri*16 + n16;
      af[ri] = *(const short8*)&xt_[m*64 + (((ks*4+q) ^ (m & 7)))*8];
    }
#pragma unroll
    for (int ci = 0; ci < 2; ci++) {
      int col = cb + ci*16 + n16;
      short8 bS = *(const short8*)(sW1t + col*128 + (ks*4+q)*8);
      short8 bT = *(const short8*)(tW1t + col*128 + (ks*4+q)*8);
#pragma unroll
      for (int ri = 0; ri < 4; ri++) {
        aS[ri][ci] = __builtin_amdgcn_mfma_f32_16x16x32_bf16(af[ri], bS, aS[ri][ci], 0, 0, 0);
        aT[ri][ci] = __builtin_amdgcn_mfma_f32_16x16x32_bf16(af[ri], bT, aT[ri][ci], 0, 0, 0);
      }
    }
  }
#pragma unroll
  for (int ri = 0; ri < 4; ri++)
#pragma unroll
    for (int ci = 0; ci < 2; ci++) {
      int col = cb + ci*16 + n16;
#pragma unroll
      for (int r = 0; r < 4; r++) {
        int row = rowbase + ri*16 + q*4 + r;
        PS[(size_t)row*128 + col] = aS[ri][ci][r];
        PT[(size_t)row*128 + col] = aT[ri][ci][r];
      }
    }
}

// ---------------- D-build: D = bf16(xj - xi), pre-swizzled per 64-row tile ----------------
// graph pinned to XCD via blockIdx&15 (16 == 0 mod 8).
__global__ __launch_bounds__(256) void dbuild_kernel(
    const float* __restrict__ x, const int* __restrict__ nbr,
    unsigned short* __restrict__ D) {
  int g = blockIdx.x & 15, chunk = blockIdx.x >> 4;
  int r4 = threadIdx.x >> 2, part = threadIdx.x & 3;
#pragma unroll
  for (int it = 0; it < 8; it++) {
    int s = g*32768 + chunk*512 + it*64 + r4;
    int node = s >> 4;
    int ng = nbr[s];
    const float4* xi = (const float4*)(x + (size_t)node * NC) + part*4;
    const float4* xj = (const float4*)(x + (size_t)ng  * NC) + part*4;
    unsigned short* dst = D + ((size_t)(s >> 6)) * 4096 + (size_t)(s & 63) * 64;
#pragma unroll
    for (int cc = 0; cc < 2; cc++) {
      int c = part*2 + cc;
      float4 a0 = xi[cc*2], a1 = xi[cc*2+1];
      float4 b0 = xj[cc*2], b1 = xj[cc*2+1];
      int pos = (c ^ (s & 7)) * 8;
      unsigned short* d = dst + pos;
      d[0]=f2bf(b0.x-a0.x); d[1]=f2bf(b0.y-a0.y); d[2]=f2bf(b0.z-a0.z); d[3]=f2bf(b0.w-a0.w);
      d[4]=f2bf(b1.x-a1.x); d[5]=f2bf(b1.y-a1.y); d[6]=f2bf(b1.z-a1.z); d[7]=f2bf(b1.w-a1.w);
    }
  }
}

// ---------------- BN passes over materialized D + per-node P ----------------
// MODE 0: h1 = P + D@W1bot -> stats1 (both streams)
// MODE 1: -> bn1+relu -> GEMM2 -> stats2
// MODE 2: -> bn2+relu -> max over K -> xout
template<int MODE>
__global__ __launch_bounds__(256, 2) void mlp_pass2(
    const unsigned short* __restrict__ D,
    const float* __restrict__ PS, const float* __restrict__ PT,
    const unsigned short* __restrict__ sW1t, const unsigned short* __restrict__ sW2t,
    const unsigned short* __restrict__ tW1t, const unsigned short* __restrict__ tW2t,
    const float* __restrict__ affS1, const float* __restrict__ affS2,
    const float* __restrict__ affT1, const float* __restrict__ affT2,
    float* __restrict__ statS, float* __restrict__ statT,
    float* __restrict__ xoutS, float* __restrict__ xoutT) {
  __shared__ unsigned short dlds[64*64];
  __shared__ unsigned short atile[(MODE >= 1) ? 64*128 : 64];
  int wave = threadIdx.x >> 6;
  int lane = threadIdx.x & 63;
  int n16 = lane & 15, q = lane >> 4;
  int cb = wave * 32;

  float s1S[2], h1S[2], s2S[2], h2S[2];
  float s1T[2], h1T[2], s2T[2], h2T[2];
  if (MODE >= 1) {
#pragma unroll
    for (int ci = 0; ci < 2; ci++) {
      int col = cb + ci*16 + n16;
      s1S[ci] = affS1[col]; h1S[ci] = affS1[128 + col];
      s1T[ci] = affT1[col]; h1T[ci] = affT1[128 + col];
    }
  }
  if (MODE == 2) {
#pragma unroll
    for (int ci = 0; ci < 2; ci++) {
      int col = cb + ci*16 + n16;
      s2S[ci] = affS2[col]; h2S[ci] = affS2[128 + col];
      s2T[ci] = affT2[col]; h2T[ci] = affT2[128 + col];
    }
  }
  float psS[2] = {0,0}, ps2S[2] = {0,0};
  float psT[2] = {0,0}, ps2T[2] = {0,0};

  for (int it = 0; it < 4; it++) {
    int tile = blockIdx.x*4 + it;
    __syncthreads();
    {
      const ushort8* src = (const ushort8*)(D + (size_t)tile*4096);
      ushort8* dst = (ushort8*)dlds;
      dst[threadIdx.x] = src[threadIdx.x];
      dst[threadIdx.x + 256] = src[threadIdx.x + 256];
    }
    __syncthreads();
    int node0 = tile*4;
    float pS[4][2], pT[4][2];
#pragma unroll
    for (int ri = 0; ri < 4; ri++)
#pragma unroll
      for (int ci = 0; ci < 2; ci++) {
        int col = cb + ci*16 + n16;
        pS[ri][ci] = PS[(size_t)(node0+ri)*128 + col];
        pT[ri][ci] = PT[(size_t)(node0+ri)*128 + col];
      }

#pragma unroll
    for (int st = 0; st < 2; st++) {
      const unsigned short* W1t = st ? tW1t : sW1t;
      const unsigned short* W2t = st ? tW2t : sW2t;
      const float* sc1 = st ? s1T : s1S;  const float* sh1 = st ? h1T : h1S;
      const float* sc2 = st ? s2T : s2S;  const float* sh2 = st ? h2T : h2S;
      float (*pp)[2] = st ? pT : pS;
      float* ps  = st ? psT : psS;
      float* ps2 = st ? ps2T : ps2S;
      float* xout = st ? xoutT : xoutS;

      // GEMM1 (bottom half, K=64): h1 = P + D @ W1bot
      f32x4 acc[4][2];
#pragma unroll
      for (int ri = 0; ri < 4; ri++)
#pragma unroll
        for (int ci = 0; ci < 2; ci++)
          acc[ri][ci] = (f32x4){0.f,0.f,0.f,0.f};
#pragma unroll
      for (int ks = 0; ks < 2; ks++) {
        short8 af[4], bf[2];
#pragma unroll
        for (int ri = 0; ri < 4; ri++) {
          int m = ri*16 + n16;
          af[ri] = *(const short8*)&dlds[m*64 + ((ks*4+q) ^ (m & 7))*8];
        }
#pragma unroll
        for (int ci = 0; ci < 2; ci++) {
          int col = cb + ci*16 + n16;
          bf[ci] = *(const short8*)(W1t + col*128 + 64 + (ks*4+q)*8);
        }
#pragma unroll
        for (int ri = 0; ri < 4; ri++)
#pragma unroll
          for (int ci = 0; ci < 2; ci++)
            acc[ri][ci] = __builtin_amdgcn_mfma_f32_16x16x32_bf16(af[ri], bf[ci], acc[ri][ci], 0, 0, 0);
      }
      if (MODE == 0) {
#pragma unroll
        for (int ci = 0; ci < 2; ci++)
#pragma unroll
          for (int ri = 0; ri < 4; ri++)
#pragma unroll
            for (int r = 0; r < 4; r++) {
              float v = acc[ri][ci][r] + pp[ri][ci];
              ps[ci] += v; ps2[ci] += v*v;
            }
        continue;
      }
      // bn1 + relu -> a-tile (bf16, swizzled)
#pragma unroll
      for (int ri = 0; ri < 4; ri++)
#pragma unroll
        for (int ci = 0; ci < 2; ci++) {
          int colL = cb + ci*16 + n16;
          int kc8 = colL >> 3;
#pragma unroll
          for (int r = 0; r < 4; r++) {
            float v = acc[ri][ci][r] + pp[ri][ci];
            v = fmaxf(v * sc1[ci] + sh1[ci], 0.f);
            int rowL = ri*16 + q*4 + r;
            int pos = ((kc8 ^ (rowL & 7)) << 3) + (colL & 7);
            atile[rowL*128 + pos] = f2bf(v);
          }
        }
      __syncthreads();
      // GEMM2 (K=128)
      f32x4 acc2[4][2];
#pragma unroll
      for (int ri = 0; ri < 4; ri++)
#pragma unroll
        for (int ci = 0; ci < 2; ci++)
          acc2[ri][ci] = (f32x4){0.f,0.f,0.f,0.f};
#pragma unroll
      for (int ks = 0; ks < 4; ks++) {
        short8 a2[4], bf[2];
#pragma unroll
        for (int ri = 0; ri < 4; ri++) {
          int mm = ri*16 + n16;
          int kc8 = (ks*4 + q) ^ (mm & 7);
          a2[ri] = *(const short8*)&atile[mm*128 + kc8*8];
        }
#pragma unroll
        for (int ci = 0; ci < 2; ci++) {
          int col = cb + ci*16 + n16;
          bf[ci] = *(const short8*)(W2t + col*128 + ks*32 + q*8);
        }
#pragma unroll
        for (int ri = 0; ri < 4; ri++)
#pragma unroll
          for (int ci = 0; ci < 2; ci++)
            acc2[ri][ci] = __builtin_amdgcn_mfma_f32_16x16x32_bf16(a2[ri], bf[ci], acc2[ri][ci], 0, 0, 0);
      }
      if (MODE == 1) {
#pragma unroll
        for (int ci = 0; ci < 2; ci++)
#pragma unroll
          for (int ri = 0; ri < 4; ri++)
#pragma unroll
            for (int r = 0; r < 4; r++) {
              float v = acc2[ri][ci][r];
              ps[ci] += v; ps2[ci] += v*v;
            }
      } else {
#pragma unroll
        for (int ri = 0; ri < 4; ri++)
#pragma unroll
          for (int ci = 0; ci < 2; ci++) {
            int col = cb + ci*16 + n16;
            float vm = 0.f;
#pragma unroll
            for (int r = 0; r < 4; r++) {
              float v = fmaxf(acc2[ri][ci][r] * sc2[ci] + sh2[ci], 0.f);
              vm = fmaxf(vm, v);
            }
            vm = fmaxf(vm, __shfl_xor(vm, 16, 64));
            vm = fmaxf(vm, __shfl_xor(vm, 32, 64));
            if (q == 0) xout[(size_t)(node0 + ri)*128 + col] = vm;
          }
      }
      if (st == 0) __syncthreads();
    }
  }
  if (MODE <= 1) {
#pragma unroll
    for (int ci = 0; ci < 2; ci++) {
      int col = cb + ci*16 + n16;
      float a = psS[ci], a2 = ps2S[ci], b = psT[ci], b2 = ps2T[ci];
      a  += __shfl_xor(a, 16, 64);  a  += __shfl_xor(a, 32, 64);
      a2 += __shfl_xor(a2, 16, 64); a2 += __shfl_xor(a2, 32, 64);
      b  += __shfl_xor(b, 16, 64);  b  += __shfl_xor(b, 32, 64);
      b2 += __shfl_xor(b2, 16, 64); b2 += __shfl_xor(b2, 32, 64);
      if (q == 0) {
        atomicAdd(&statS[col], a);
        atomicAdd(&statS[128 + col], a2);
        atomicAdd(&statT[col], b);
        atomicAdd(&statT[128 + col], b2);
      }
    }
  }
}

// ---------------- finalize BN stats -> (scale, shift) ----------------
__global__ void finalize_kernel(const float* __restrict__ stats,
                                const float* __restrict__ g,
                                const float* __restrict__ be,
                                float* __restrict__ aff, float invcount) {
  int c = threadIdx.x;
  if (c < 128) {
    float mean = stats[c] * invcount;
    float var = stats[128 + c] * invcount - mean*mean;
    float scale = g[c] / sqrtf(var + EPSV);
    aff[c] = scale;
    aff[128 + c] = be[c] - mean * scale;
  }
}

// ---------------- final linear ----------------
__global__ __launch_bounds__(128) void final_pass(
    const float* __restrict__ xs,
    const float* __restrict__ xt,
    const unsigned short* __restrict__ fWt,
    float* __restrict__ gout,
    float* __restrict__ stats) {
  __shared__ unsigned short tile[64 * 256];
  int wave = threadIdx.x >> 6, lane = threadIdx.x & 63;
  int n16 = lane & 15, q = lane >> 4;
  int cb = wave * 64;
  int s0 = blockIdx.x * 64;
  {
    int r = threadIdx.x >> 1, half = threadIdx.x & 1;
    const float4* src = (const float4*)((half ? xt : xs) + (size_t)(s0 + r) * 128);
#pragma unroll
    for (int kk = 0; kk < 32; kk++) {
      float4 v = src[kk];
      int kc8 = half*16 + (kk >> 1);
      int pos = ((kc8 ^ (r & 7)) << 3) + ((kk & 1) << 2);
      unsigned short* d = &tile[r*256 + pos];
      d[0]=f2bf(v.x); d[1]=f2bf(v.y); d[2]=f2bf(v.z); d[3]=f2bf(v.w);
    }
  }
  __syncthreads();
  f32x4 acc[4][4];
#pragma unroll
  for (int ri = 0; ri < 4; ri++)
#pragma unroll
    for (int ci = 0; ci < 4; ci++)
      acc[ri][ci] = (f32x4){0.f,0.f,0.f,0.f};
#pragma unroll
  for (int ks = 0; ks < 8; ks++) {
    short8 af[4], bf[4];
#pragma unroll
    for (int ri = 0; ri < 4; ri++) {
      int mm = ri*16 + n16;
      int kc8 = (ks*4 + q) ^ (mm & 7);
      af[ri] = *(const short8*)&tile[mm*256 + kc8*8];
    }
#pragma unroll
    for (int ci = 0; ci < 4; ci++) {
      int col = cb + ci*16 + n16;
      bf[ci] = *(const short8*)(fWt + col*256 + ks*32 + q*8);
    }
#pragma unroll
    for (int ri = 0; ri < 4; ri++)
#pragma unroll
      for (int ci = 0; ci < 4; ci++)
        acc[ri][ci] = __builtin_amdgcn_mfma_f32_16x16x32_bf16(af[ri], bf[ci], acc[ri][ci], 0, 0, 0);
  }
  float ps[4] = {0,0,0,0}, ps2[4] = {0,0,0,0};
#pragma unroll
  for (int ri = 0; ri < 4; ri++)
#pragma unroll
    for (int ci = 0; ci < 4; ci++) {
      int col = cb + ci*16 + n16;
#pragma unroll
      for (int r = 0; r < 4; r++) {
        float v = acc[ri][ci][r];
        int row = s0 + ri*16 + q*4 + r;
        gout[(size_t)row*128 + col] = v;
        ps[ci] += v; ps2[ci] += v*v;
      }
    }
#pragma unroll
  for (int ci = 0; ci < 4; ci++) {
    float s = ps[ci], s2 = ps2[ci];
    s  += __shfl_xor(s, 16, 64);  s  += __shfl_xor(s, 32, 64);
    s2 += __shfl_xor(s2, 16, 64); s2 += __shfl_xor(s2, 32, 64);
    if (q == 0) {
      int col = cb + ci*16 + n16;
      atomicAdd(&stats[col], s);
      atomicAdd(&stats[128 + col], s2);
    }
  }
}

__global__ void apply_bn_kernel(float* __restrict__ out, const float* __restrict__ aff) {
  int i = blockIdx.x * blockDim.x + threadIdx.x;
  if (i < NS*NH) {
    int c = i & 127;
    out[i] = fmaxf(out[i] * aff[c] + aff[128 + c], 0.f);
  }
}

extern "C" void kernel_launch(void* const* d_in, const int* in_sizes, int n_in,
                              void* d_out, int out_size, void* d_ws, size_t ws_size,
                              hipStream_t stream) {
  const float* x   = (const float*)d_in[0];
  const float* sW1 = (const float*)d_in[2];
  const float* sg1 = (const float*)d_in[4];
  const float* sbe1= (const float*)d_in[5];
  const float* sW2 = (const float*)d_in[6];
  const float* sg2 = (const float*)d_in[8];
  const float* sbe2= (const float*)d_in[9];
  const float* tW1 = (const float*)d_in[10];
  const float* tg1 = (const float*)d_in[12];
  const float* tbe1= (const float*)d_in[13];
  const float* tW2 = (const float*)d_in[14];
  const float* tg2 = (const float*)d_in[16];
  const float* tbe2= (const float*)d_in[17];
  const float* fW  = (const float*)d_in[18];
  const float* fg  = (const float*)d_in[20];
  const float* fbe = (const float*)d_in[21];
  float* out = (float*)d_out;

  char* w = (char*)d_ws;
  float* sq = (float*)w;                 w += (size_t)NS*4;
  int* nbr = (int*)w;                    w += (size_t)NSK*4;
  unsigned short* sW1t = (unsigned short*)w; w += 32768;
  unsigned short* sW2t = (unsigned short*)w; w += 32768;
  unsigned short* tW1t = (unsigned short*)w; w += 32768;
  unsigned short* tW2t = (unsigned short*)w; w += 32768;
  unsigned short* fWt  = (unsigned short*)w; w += 65536;
  float* stats = (float*)w;              w += 2560*4;
  float* xs = (float*)w;                 w += (size_t)NS*NH*4;
  float* xt = (float*)w;                 w += (size_t)NS*NH*4;
  unsigned short* xh = (unsigned short*)w; w += (size_t)NS*64*2;
  unsigned short* xl = (unsigned short*)w; w += (size_t)NS*64*2;
  unsigned short* Dg = (unsigned short*)w; w += (size_t)NSK*64*2;
  float* PS = (float*)w;                 w += (size_t)NS*128*4;
  float* PT = (float*)w;                 w += (size_t)NS*128*4;

  float* st_s1 = stats;        float* af_s1 = stats + 256;
  float* st_s2 = stats + 512;  float* af_s2 = stats + 768;
  float* st_t1 = stats + 1024; float* af_t1 = stats + 1280;
  float* st_t2 = stats + 1536; float* af_t2 = stats + 1792;
  float* st_f  = stats + 2048; float* af_f  = stats + 2304;

  hipMemsetAsync(stats, 0, 2560*4, stream);
  prep_weights<<<(4*16384 + 128*256 + 255)/256, 256, 0, stream>>>(
      sW1, sW2, tW1, tW2, fW, sW1t, sW2t, tW1t, tW2t, fWt);
  prep_x<<<NS/256, 256, 0, stream>>>(x, sq, xh, xl);
  knn3_kernel<<<NB*32, 256, 0, stream>>>(xh, xl, sq, nbr);
  pnode_kernel<<<NS/64, 256, 0, stream>>>(x, sW1t, tW1t, PS, PT);
  dbuild_kernel<<<1024, 256, 0, stream>>>(x, nbr, Dg);

  const float inv1 = 1.f/(float)NSK, invf = 1.f/(float)NS;
  mlp_pass2<0><<<2048,256,0,stream>>>(Dg, PS, PT, sW1t, sW2t, tW1t, tW2t,
      nullptr, nullptr, nullptr, nullptr, st_s1, st_t1, nullptr, nullptr);
  finalize_kernel<<<1,128,0,stream>>>(st_s1, sg1, sbe1, af_s1, inv1);
  finalize_kernel<<<1,128,0,stream>>>(st_t1, tg1, tbe1, af_t1, inv1);
  mlp_pass2<1><<<2048,256,0,stream>>>(Dg, PS, PT, sW1t, sW2t, tW1t, tW2t,
      af_s1, nullptr, af_t1, nullptr, st_s2, st_t2, nullptr, nullptr);
  finalize_kernel<<<1,128,0,stream>>>(st_s2, sg2, sbe2, af_s2, inv1);
  finalize_kernel<<<1,128,0,stream>>>(st_t2, tg2, tbe2, af_t2, inv1);
  mlp_pass2<2><<<2048,256,0,stream>>>(Dg, PS, PT, sW1t, sW2t, tW1t, tW2t,
      af_s1, af_s2, af_t1, af_t2, nullptr, nullptr, xs, xt);
  final_pass<<<NS/64, 128, 0, stream>>>(xs, xt, fWt, out, st_f);
  finalize_kernel<<<1,128,0,stream>>>(st_f, fg, fbe, af_f, invf);
  apply_bn_kernel<<<(NS*NH)/256, 256, 0, stream>>>(out, af_f);
}